// Round 10
// baseline (5681.270 us; speedup 1.0000x reference)
//
#include <hip/hip_runtime.h>
#include <math.h>

#define T_ 1024
#define NT_ 4096
#define MASKSELF64 -50000.0
#define MASKSELF32 -50000.0f
// WORKSPACE CONSTRAINT (R9 post-mortem): ws_size ~= 256MB. R0/R9 wrote past 256M
// -> intermittent OOB garbage / SIGABRT. Keep ALL buffers <= 241MB (R8-proven).

// ---------------- embedding (fp64) ----------------
__global__ __launch_bounds__(256)
void embed_kernel(const float* __restrict__ x_enc, const float* __restrict__ x_mark_enc,
                  const float* __restrict__ x_dec, const float* __restrict__ x_mark_dec,
                  const float* __restrict__ conv_w, const float* __restrict__ mark_w,
                  double* __restrict__ h) {
  int bt = blockIdx.x;
  int b = bt >> 10, t = bt & 1023;
  __shared__ double xs[3][7];
  __shared__ double xm[4];
  int tid = threadIdx.x;
  if (tid < 21) {
    int k = tid / 7, i = tid % 7;
    int tt = t + k - 1;
    if (tt < 0) tt += 1024;
    if (tt >= 1024) tt -= 1024;
    xs[k][i] = (double)((tt < 768) ? x_enc[((size_t)b*768 + tt)*7 + i]
                                   : x_dec[((size_t)b*512 + (tt - 512))*7 + i]);
  }
  if (tid >= 32 && tid < 36) {
    int m = tid - 32;
    xm[m] = (double)((t < 768) ? x_mark_enc[((size_t)b*768 + t)*4 + m]
                               : x_mark_dec[((size_t)b*512 + (t - 512))*4 + m]);
  }
  __syncthreads();
  for (int o = tid; o < 512; o += 256) {
    double acc = 0.0;
    #pragma unroll
    for (int k = 0; k < 3; ++k)
      #pragma unroll
      for (int i = 0; i < 7; ++i)
        acc += xs[k][i] * (double)conv_w[(o*7 + i)*3 + k];
    #pragma unroll
    for (int m = 0; m < 4; ++m) acc += xm[m] * (double)mark_w[m*512 + o];
    int j2 = o & ~1;
    double dv = exp((double)j2 * (-9.210340371976184 / 512.0));
    double arg = (double)t * dv;
    acc += (o & 1) ? cos(arg) : sin(arg);
    h[((size_t)b*1024 + t)*512 + o] = acc;
  }
}

// ---------------- fp64 scalar GEMM 128x128, K-step 32, 8x8 microtile, reg dbuf ----------------
// Per-output arithmetic BIT-IDENTICAL to R6-R8 (same ascending-k FMA chain, same epilogue).
// flags: 1=+bias, 2=gelu(exact), 4=qkv layout, 8=dup f32 store (qkv only), 16=accumulate into C
__global__ __launch_bounds__(256)
void dgemm_kernel(const double* __restrict__ A, const float* __restrict__ Bm,
                  const float* __restrict__ bias, double* __restrict__ C,
                  float* __restrict__ C32, int N, int K, int ldb, int flags) {
  __shared__ double As[32][130];
  __shared__ float  Bs[32][132];
  int tid = threadIdx.x;
  int tx = tid & 15, ty = tid >> 4;
  int arow = blockIdx.x * 128;
  int bcol = blockIdx.y * 128;
  int aty = ty, akx = tx*2;
  int bky = tid >> 5, bcx = (tid & 31)*4;
  const double* aptr = A + (size_t)(arow + aty)*K + akx;
  const float*  bptr = Bm + (size_t)bky*ldb + bcol + bcx;
  double acc[8][8];
  #pragma unroll
  for (int i=0;i<8;++i)
    #pragma unroll
    for (int j=0;j<8;++j) acc[i][j]=0.0;
  double2 va[8];
  float4  vb[4];
  #pragma unroll
  for (int q=0;q<8;++q) va[q] = *(const double2*)(aptr + (size_t)q*16*K);
  #pragma unroll
  for (int q=0;q<4;++q) vb[q] = *(const float4*)(bptr + (size_t)q*8*ldb);
  for (int k0 = 0; k0 < K; k0 += 32) {
    #pragma unroll
    for (int q=0;q<8;++q) { As[akx][q*16+aty] = va[q].x; As[akx+1][q*16+aty] = va[q].y; }
    #pragma unroll
    for (int q=0;q<4;++q) *(float4*)&Bs[bky + q*8][bcx] = vb[q];
    __syncthreads();
    if (k0 + 32 < K) {
      aptr += 32;
      bptr += (size_t)32*ldb;
      #pragma unroll
      for (int q=0;q<8;++q) va[q] = *(const double2*)(aptr + (size_t)q*16*K);
      #pragma unroll
      for (int q=0;q<4;++q) vb[q] = *(const float4*)(bptr + (size_t)q*8*ldb);
    }
    #pragma unroll
    for (int kk=0;kk<32;++kk) {
      double a[8];
      *(double2*)&a[0] = *(const double2*)&As[kk][2*ty];
      *(double2*)&a[2] = *(const double2*)&As[kk][2*ty+32];
      *(double2*)&a[4] = *(const double2*)&As[kk][2*ty+64];
      *(double2*)&a[6] = *(const double2*)&As[kk][2*ty+96];
      float2 f0 = *(const float2*)&Bs[kk][2*tx];
      float2 f1 = *(const float2*)&Bs[kk][2*tx+32];
      float2 f2 = *(const float2*)&Bs[kk][2*tx+64];
      float2 f3 = *(const float2*)&Bs[kk][2*tx+96];
      double b[8];
      b[0]=(double)f0.x; b[1]=(double)f0.y; b[2]=(double)f1.x; b[3]=(double)f1.y;
      b[4]=(double)f2.x; b[5]=(double)f2.y; b[6]=(double)f3.x; b[7]=(double)f3.y;
      #pragma unroll
      for (int i=0;i<8;++i)
        #pragma unroll
        for (int j=0;j<8;++j) acc[i][j] += a[i]*b[j];
    }
    __syncthreads();
  }
  #pragma unroll
  for (int i=0;i<8;++i) {
    int row = arow + 2*ty + (i&1) + 32*(i>>1);
    #pragma unroll
    for (int j=0;j<8;++j) {
      int col = bcol + 2*tx + (j&1) + 32*(j>>1);
      double cv = acc[i][j];
      if (flags & 1) cv += (double)bias[col];
      if (flags & 2) cv = 0.5*cv*(1.0 + erf(cv*0.70710678118654752440));
      if (flags & 4) {
        int b_ = row >> 10, t = row & 1023;
        int hd = col >> 6, dd = col & 63;
        size_t idx = (((size_t)b_*8 + hd)*1024 + t)*64 + dd;
        C[idx] = cv;
        if (flags & 8) C32[idx] = (float)cv;
      } else {
        size_t idx = (size_t)row*N + col;
        if (flags & 16) cv += C[idx];
        C[idx] = cv;
      }
    }
  }
}

// ---------------- fp32 GEMM 128x128, K-step 32, 8x8 microtile, reg dbuf ----------------
// flags: 1=+bias, 2=gelu(exact), 4=qkv layout
__global__ __launch_bounds__(256)
void sgemm_kernel(const float* __restrict__ A, const float* __restrict__ Bm,
                  const float* __restrict__ bias, float* __restrict__ C,
                  int N, int K, int flags) {
  __shared__ float As[32][132];
  __shared__ float Bs[32][132];
  int tid = threadIdx.x;
  int tx = tid & 15, ty = tid >> 4;
  float acc[8][8];
  #pragma unroll
  for (int i=0;i<8;++i)
    #pragma unroll
    for (int j=0;j<8;++j) acc[i][j]=0.f;
  const int arow = blockIdx.x*128;
  const int bcol = blockIdx.y*128;
  int ary = tid >> 3, acx = (tid & 7)*4;
  int bky = tid >> 5, bcx = (tid & 31)*4;
  const float* pA = A + (size_t)(arow + ary)*K + acx;
  const float* pB = Bm + (size_t)bky*N + bcol + bcx;
  float4 va[4], vb[4];
  #pragma unroll
  for (int q=0;q<4;++q) va[q] = *(const float4*)(pA + (size_t)q*32*K);
  #pragma unroll
  for (int q=0;q<4;++q) vb[q] = *(const float4*)(pB + (size_t)q*8*N);
  for (int k0 = 0; k0 < K; k0 += 32) {
    #pragma unroll
    for (int q=0;q<4;++q) {
      As[acx+0][q*32+ary]=va[q].x; As[acx+1][q*32+ary]=va[q].y;
      As[acx+2][q*32+ary]=va[q].z; As[acx+3][q*32+ary]=va[q].w;
      *(float4*)&Bs[bky + q*8][bcx] = vb[q];
    }
    __syncthreads();
    if (k0 + 32 < K) {
      pA += 32;
      pB += (size_t)32*N;
      #pragma unroll
      for (int q=0;q<4;++q) va[q] = *(const float4*)(pA + (size_t)q*32*K);
      #pragma unroll
      for (int q=0;q<4;++q) vb[q] = *(const float4*)(pB + (size_t)q*8*N);
    }
    #pragma unroll
    for (int kk=0;kk<32;++kk) {
      float a[8], bb[8];
      #pragma unroll
      for (int i=0;i<8;++i) a[i] = As[kk][ty + 16*i];
      #pragma unroll
      for (int j=0;j<8;++j) bb[j] = Bs[kk][tx + 16*j];
      #pragma unroll
      for (int i=0;i<8;++i)
        #pragma unroll
        for (int j=0;j<8;++j) acc[i][j] += a[i]*bb[j];
    }
    __syncthreads();
  }
  #pragma unroll
  for (int i=0;i<8;++i) {
    int row = arow + ty + 16*i;
    #pragma unroll
    for (int j=0;j<8;++j) {
      int col = bcol + tx + 16*j;
      float cv = acc[i][j];
      if (flags & 1) cv += bias[col];
      if (flags & 2) cv = 0.5f*cv*(1.0f + erff(cv*0.70710678118654752f));
      if (flags & 4) {
        int b = row >> 10, t = row & 1023;
        int hd = col >> 6, dd = col & 63;
        C[(((size_t)b*8 + hd)*1024 + t)*64 + dd] = cv;
      } else {
        C[(size_t)row*N + col] = cv;
      }
    }
  }
}

// ---------------- LSH bucket assignment + parallel two-level counting sort (fp64) ----------------
// Output IDENTICAL to the serial stable placement: within a bucket, tokens ascend.
__global__ __launch_bounds__(256)
void bucket_sort_kernel(const double* __restrict__ qk, const float* __restrict__ rot,
                        int* __restrict__ sticker) {
  int bh = blockIdx.x >> 2, r = blockIdx.x & 3;
  __shared__ double rots[64][17];
  __shared__ unsigned char bucket[1024];
  __shared__ int cnt[32];
  __shared__ short H[16][32];
  __shared__ int off2[16][32];
  int tid = threadIdx.x;
  for (int idx = tid; idx < 1024; idx += 256) {
    int f = idx >> 4, i = idx & 15;
    rots[f][i] = (double)rot[(f*4 + r)*16 + i];
  }
  __syncthreads();
  for (int t = tid; t < 1024; t += 256) {
    const double* q = qk + ((size_t)bh*1024 + t)*64;
    double rv[16];
    #pragma unroll
    for (int i=0;i<16;++i) rv[i]=0.0;
    for (int f=0; f<64; ++f) {
      double qf = q[f];
      #pragma unroll
      for (int i=0;i<16;++i) rv[i] += qf * rots[f][i];
    }
    int best = 0; double bv = rv[0];
    #pragma unroll
    for (int i=1;i<16;++i) if (rv[i] > bv) { bv=rv[i]; best=i; }
    #pragma unroll
    for (int i=0;i<16;++i) { double nv = -rv[i]; if (nv > bv) { bv=nv; best=16+i; } }
    bucket[t] = (unsigned char)best;
  }
  __syncthreads();
  {
    int c = tid >> 4, s = tid & 15;
    int h0 = 0, h1 = 0;
    for (int t = c*64; t < c*64 + 64; ++t) {
      int b = bucket[t];
      h0 += (b == s);
      h1 += (b == s + 16);
    }
    H[c][s] = (short)h0;
    H[c][s+16] = (short)h1;
  }
  __syncthreads();
  if (tid < 32) {
    int s = 0;
    for (int c = 0; c < 16; ++c) s += H[c][tid];
    cnt[tid] = s;
  }
  __syncthreads();
  if (tid < 32) {
    int o = 0;
    for (int b = 0; b < tid; ++b) o += cnt[b];
    for (int c = 0; c < 16; ++c) { off2[c][tid] = o; o += H[c][tid]; }
  }
  __syncthreads();
  int* outp = sticker + (size_t)bh*NT_ + r*1024;
  #pragma unroll
  for (int q = 0; q < 2; ++q) {
    int p = tid + q*256;
    int c = p >> 5, b = p & 31;
    int pos = off2[c][b];
    for (int t = c*64; t < c*64 + 64; ++t)
      if (bucket[t] == (unsigned char)b) outp[pos++] = t;
  }
}

// ---------------- chunked LSH attention fp64 (16-bh groups, bh-global lse) ----------------
__global__ __launch_bounds__(256)
void lsh_attn_kernel(const double* __restrict__ qk, const double* __restrict__ v,
                     const int* __restrict__ sticker,
                     double* __restrict__ obuf, double* __restrict__ lse, int bh0) {
  int bh_l = blockIdx.x >> 7;
  int bh = bh0 + bh_l;
  int c  = blockIdx.x & 127;
  int cprev = (c + 127) & 127;
  __shared__ double kv[64][66];
  __shared__ double pp[32][66];
  __shared__ double rnorm[64];
  __shared__ int tk[64];
  int tid = threadIdx.x;
  if (tid < 64) {
    int chunk = (tid < 32) ? c : cprev;
    tk[tid] = sticker[(size_t)bh*NT_ + chunk*32 + (tid & 31)];
  }
  __syncthreads();
  for (int idx = tid; idx < 2048; idx += 256) {
    int j = idx >> 5, c2 = (idx & 31)*2;
    *(double2*)&kv[j][c2] = *(const double2*)(qk + ((size_t)bh*1024 + tk[j])*64 + c2);
  }
  __syncthreads();
  if (tid < 64) {
    double s = 0.0;
    #pragma unroll
    for (int f=0; f<64; ++f) { double x = kv[tid][f]; s += x*x; }
    rnorm[tid] = 1.0 / fmax(sqrt(s), 1e-12);
  }
  __syncthreads();
  int i = tid >> 3, sub = tid & 7;
  int ti = tk[i];
  double dots[8];
  double dmax = -1.0e300;
  #pragma unroll
  for (int jj=0; jj<8; ++jj) {
    int j = sub*8 + jj;
    double s = 0.0;
    #pragma unroll
    for (int f=0; f<64; ++f) s += kv[i][f] * kv[j][f];
    s *= rnorm[j] * 0.125;
    if (ti == tk[j]) s = MASKSELF64;
    dots[jj] = s;
    dmax = fmax(dmax, s);
  }
  #pragma unroll
  for (int w=1; w<8; w<<=1) dmax = fmax(dmax, __shfl_xor(dmax, w, 64));
  double esum = 0.0;
  #pragma unroll
  for (int jj=0; jj<8; ++jj) {
    double e = exp(dots[jj] - dmax);
    esum += e;
    pp[i][sub*8+jj] = e;
  }
  #pragma unroll
  for (int w=1; w<8; w<<=1) esum += __shfl_xor(esum, w, 64);
  __syncthreads();
  for (int idx = tid; idx < 2048; idx += 256) {
    int j = idx >> 5, c2 = (idx & 31)*2;
    *(double2*)&kv[j][c2] = *(const double2*)(v + ((size_t)bh*1024 + tk[j])*64 + c2);
  }
  __syncthreads();
  double ov[8];
  #pragma unroll
  for (int dd=0;dd<8;++dd) ov[dd]=0.0;
  for (int j=0;j<64;++j) {
    double p = pp[i][j];
    #pragma unroll
    for (int dd=0;dd<8;++dd) ov[dd] += p * kv[j][sub*8+dd];
  }
  double rinv = 1.0 / esum;
  int r = c >> 5;
  size_t ob = (((size_t)bh_l*4 + r)*1024 + ti)*64 + sub*8;
  #pragma unroll
  for (int dd=0;dd<8;++dd) obuf[ob + dd] = ov[dd]*rinv;
  if (sub == 0) lse[((size_t)bh*4 + r)*1024 + ti] = log(esum) + dmax;
}

// ---------------- combine rounds fp64 (bh-global lse) ----------------
__global__ __launch_bounds__(256)
void combine_kernel(const double* __restrict__ obuf, const double* __restrict__ lse,
                    double* __restrict__ comb, int bh0) {
  int g = blockIdx.x*4 + (threadIdx.x >> 6);
  int bh_l = g >> 10, t = g & 1023;
  int bh = bh0 + bh_l;
  int d = threadIdx.x & 63;
  double l[4];
  #pragma unroll
  for (int r=0;r<4;++r) l[r] = lse[((size_t)bh*4 + r)*1024 + t];
  double m = fmax(fmax(l[0],l[1]), fmax(l[2],l[3]));
  double e[4], s=0.0;
  #pragma unroll
  for (int r=0;r<4;++r){ e[r]=exp(l[r]-m); s+=e[r]; }
  double rs = 1.0/s;
  double o = 0.0;
  #pragma unroll
  for (int r=0;r<4;++r)
    o += e[r]*rs * obuf[(((size_t)bh_l*4 + r)*1024 + t)*64 + d];
  int b = bh >> 3, hd = bh & 7;
  comb[((size_t)b*1024 + t)*512 + hd*64 + d] = o;
}

// ---------------- chunked LSH attention fp32 (32-bh groups, bh-global lse) ----------------
__global__ __launch_bounds__(256)
void lsh_attn32_kernel(const float* __restrict__ qk, const float* __restrict__ v,
                       const int* __restrict__ sticker,
                       float* __restrict__ obuf, float* __restrict__ lse, int bh0) {
  int bh_l = blockIdx.x >> 7;
  int bh = bh0 + bh_l;
  int c  = blockIdx.x & 127;
  int cprev = (c + 127) & 127;
  __shared__ float kv[64][68];
  __shared__ float pp[32][68];
  __shared__ float rnorm[64];
  __shared__ int tk[64];
  int tid = threadIdx.x;
  if (tid < 64) {
    int chunk = (tid < 32) ? c : cprev;
    tk[tid] = sticker[(size_t)bh*NT_ + chunk*32 + (tid & 31)];
  }
  __syncthreads();
  for (int idx = tid; idx < 1024; idx += 256) {
    int j = idx >> 4, c4 = (idx & 15)*4;
    *(float4*)&kv[j][c4] = *(const float4*)(qk + ((size_t)bh*1024 + tk[j])*64 + c4);
  }
  __syncthreads();
  if (tid < 64) {
    float s = 0.f;
    #pragma unroll
    for (int f=0; f<64; ++f) { float x = kv[tid][f]; s += x*x; }
    rnorm[tid] = 1.0f / fmaxf(sqrtf(s), 1e-12f);
  }
  __syncthreads();
  int i = tid >> 3, sub = tid & 7;
  int ti = tk[i];
  float dots[8];
  float dmax = -1.0e30f;
  #pragma unroll
  for (int jj=0; jj<8; ++jj) {
    int j = sub*8 + jj;
    float s = 0.f;
    #pragma unroll
    for (int f=0; f<64; ++f) s += kv[i][f] * kv[j][f];
    s *= rnorm[j] * 0.125f;
    if (ti == tk[j]) s = MASKSELF32;
    dots[jj] = s;
    dmax = fmaxf(dmax, s);
  }
  #pragma unroll
  for (int w=1; w<8; w<<=1) dmax = fmaxf(dmax, __shfl_xor(dmax, w, 64));
  float esum = 0.f;
  #pragma unroll
  for (int jj=0; jj<8; ++jj) {
    float e = expf(dots[jj] - dmax);
    esum += e;
    pp[i][sub*8+jj] = e;
  }
  #pragma unroll
  for (int w=1; w<8; w<<=1) esum += __shfl_xor(esum, w, 64);
  __syncthreads();
  for (int idx = tid; idx < 1024; idx += 256) {
    int j = idx >> 4, c4 = (idx & 15)*4;
    *(float4*)&kv[j][c4] = *(const float4*)(v + ((size_t)bh*1024 + tk[j])*64 + c4);
  }
  __syncthreads();
  float ov[8];
  #pragma unroll
  for (int dd=0;dd<8;++dd) ov[dd]=0.f;
  for (int j=0;j<64;++j) {
    float p = pp[i][j];
    #pragma unroll
    for (int dd=0;dd<8;++dd) ov[dd] += p * kv[j][sub*8+dd];
  }
  float rinv = 1.0f / esum;
  int r = c >> 5;
  size_t ob = (((size_t)bh_l*4 + r)*1024 + ti)*64 + sub*8;
  #pragma unroll
  for (int dd=0;dd<8;++dd) obuf[ob + dd] = ov[dd]*rinv;
  if (sub == 0) lse[((size_t)bh*4 + r)*1024 + ti] = logf(esum) + dmax;
}

// ---------------- combine rounds fp32 (bh-global lse) ----------------
__global__ __launch_bounds__(256)
void combine32_kernel(const float* __restrict__ obuf, const float* __restrict__ lse,
                      float* __restrict__ comb, int bh0) {
  int g = blockIdx.x*4 + (threadIdx.x >> 6);
  int bh_l = g >> 10, t = g & 1023;
  int bh = bh0 + bh_l;
  int d = threadIdx.x & 63;
  float l[4];
  #pragma unroll
  for (int r=0;r<4;++r) l[r] = lse[((size_t)bh*4 + r)*1024 + t];
  float m = fmaxf(fmaxf(l[0],l[1]), fmaxf(l[2],l[3]));
  float e[4], s=0.f;
  #pragma unroll
  for (int r=0;r<4;++r){ e[r]=expf(l[r]-m); s+=e[r]; }
  float rs = 1.0f/s;
  float o = 0.f;
  #pragma unroll
  for (int r=0;r<4;++r)
    o += e[r]*rs * obuf[(((size_t)bh_l*4 + r)*1024 + t)*64 + d];
  int b = bh >> 3, hd = bh & 7;
  comb[((size_t)b*1024 + t)*512 + hd*64 + d] = o;
}

// ---------------- layernorm fp64 (optional residual, optional f32 dup) ----------------
__global__ __launch_bounds__(256)
void ln_kernel(const double* __restrict__ x, const double* __restrict__ res,
               const float* __restrict__ gw, const float* __restrict__ bw,
               double* __restrict__ outp, float* __restrict__ out32) {
  int row = blockIdx.x;
  int tid = threadIdx.x;
  const double* xr = x + (size_t)row*512;
  double v0 = xr[tid], v1 = xr[tid+256];
  if (res) { const double* rr = res + (size_t)row*512; v0 += rr[tid]; v1 += rr[tid+256]; }
  double s = v0 + v1;
  #pragma unroll
  for (int w=1; w<64; w<<=1) s += __shfl_xor(s, w, 64);
  __shared__ double red[4];
  int wid = tid >> 6, lane = tid & 63;
  if (lane == 0) red[wid] = s;
  __syncthreads();
  s = red[0]+red[1]+red[2]+red[3];
  double m = s * (1.0/512.0);
  double d0 = v0 - m, d1 = v1 - m;
  double q = d0*d0 + d1*d1;
  #pragma unroll
  for (int w=1; w<64; w<<=1) q += __shfl_xor(q, w, 64);
  __syncthreads();
  if (lane == 0) red[wid] = q;
  __syncthreads();
  q = red[0]+red[1]+red[2]+red[3];
  double var = q * (1.0/512.0);
  double rstd = 1.0 / sqrt(var + 1e-5);
  double o0 = d0*rstd*(double)gw[tid] + (double)bw[tid];
  double o1 = d1*rstd*(double)gw[tid+256] + (double)bw[tid+256];
  outp[(size_t)row*512 + tid]       = o0;
  outp[(size_t)row*512 + tid + 256] = o1;
  if (out32) {
    out32[(size_t)row*512 + tid]       = (float)o0;
    out32[(size_t)row*512 + tid + 256] = (float)o1;
  }
}

// ---------------- layernorm: x f64 + res f32 -> f32 ----------------
__global__ __launch_bounds__(256)
void lnmx_kernel(const double* __restrict__ x, const float* __restrict__ res,
                 const float* __restrict__ gw, const float* __restrict__ bw,
                 float* __restrict__ out32) {
  int row = blockIdx.x;
  int tid = threadIdx.x;
  const double* xr = x + (size_t)row*512;
  const float*  rr = res + (size_t)row*512;
  double v0 = xr[tid] + (double)rr[tid];
  double v1 = xr[tid+256] + (double)rr[tid+256];
  double s = v0 + v1;
  #pragma unroll
  for (int w=1; w<64; w<<=1) s += __shfl_xor(s, w, 64);
  __shared__ double red[4];
  int wid = tid >> 6, lane = tid & 63;
  if (lane == 0) red[wid] = s;
  __syncthreads();
  s = red[0]+red[1]+red[2]+red[3];
  double m = s * (1.0/512.0);
  double d0 = v0 - m, d1 = v1 - m;
  double q = d0*d0 + d1*d1;
  #pragma unroll
  for (int w=1; w<64; w<<=1) q += __shfl_xor(q, w, 64);
  __syncthreads();
  if (lane == 0) red[wid] = q;
  __syncthreads();
  q = red[0]+red[1]+red[2]+red[3];
  double rstd = 1.0 / sqrt(q * (1.0/512.0) + 1e-5);
  out32[(size_t)row*512 + tid]       = (float)(d0*rstd*(double)gw[tid] + (double)bw[tid]);
  out32[(size_t)row*512 + tid + 256] = (float)(d1*rstd*(double)gw[tid+256] + (double)bw[tid+256]);
}

// ---------------- layernorm f32 in/out (double stats), optional residual ----------------
__global__ __launch_bounds__(256)
void ln32_kernel(const float* __restrict__ x, const float* __restrict__ res,
                 const float* __restrict__ gw, const float* __restrict__ bw,
                 float* __restrict__ out32) {
  int row = blockIdx.x;
  int tid = threadIdx.x;
  const float* xr = x + (size_t)row*512;
  double v0 = (double)xr[tid], v1 = (double)xr[tid+256];
  if (res) { const float* rr = res + (size_t)row*512; v0 += (double)rr[tid]; v1 += (double)rr[tid+256]; }
  double s = v0 + v1;
  #pragma unroll
  for (int w=1; w<64; w<<=1) s += __shfl_xor(s, w, 64);
  __shared__ double red[4];
  int wid = tid >> 6, lane = tid & 63;
  if (lane == 0) red[wid] = s;
  __syncthreads();
  s = red[0]+red[1]+red[2]+red[3];
  double m = s * (1.0/512.0);
  double d0 = v0 - m, d1 = v1 - m;
  double q = d0*d0 + d1*d1;
  #pragma unroll
  for (int w=1; w<64; w<<=1) q += __shfl_xor(q, w, 64);
  __syncthreads();
  if (lane == 0) red[wid] = q;
  __syncthreads();
  q = red[0]+red[1]+red[2]+red[3];
  double rstd = 1.0 / sqrt(q * (1.0/512.0) + 1e-5);
  out32[(size_t)row*512 + tid]       = (float)(d0*rstd*(double)gw[tid] + (double)bw[tid]);
  out32[(size_t)row*512 + tid + 256] = (float)(d1*rstd*(double)gw[tid+256] + (double)bw[tid+256]);
}

// ---------------- final projection (f32 input, f64 accum, f32 store) ----------------
__global__ __launch_bounds__(64)
void proj_kernel(const float* __restrict__ hf, const float* __restrict__ pw,
                 const float* __restrict__ pb, float* __restrict__ outp) {
  int row = blockIdx.x;
  int b = row >> 8, tp = row & 255;
  const float* hr = hf + ((size_t)b*1024 + 768 + tp)*512;
  int lane = threadIdx.x;
  double acc[7];
  #pragma unroll
  for (int cc=0;cc<7;++cc) acc[cc]=0.0;
  for (int d = lane; d < 512; d += 64) {
    double hv = (double)hr[d];
    #pragma unroll
    for (int cc=0;cc<7;++cc) acc[cc] += hv * (double)pw[d*7 + cc];
  }
  #pragma unroll
  for (int cc=0;cc<7;++cc) {
    double s = acc[cc];
    #pragma unroll
    for (int w=32;w>=1;w>>=1) s += __shfl_xor(s, w, 64);
    if (lane == 0) outp[(size_t)row*7 + cc] = (float)(s + (double)pb[cc]);
  }
}

extern "C" void kernel_launch(void* const* d_in, const int* in_sizes, int n_in,
                              void* d_out, int out_size, void* d_ws, size_t ws_size,
                              hipStream_t stream) {
  (void)in_sizes; (void)n_in; (void)out_size; (void)ws_size;
  const float* x_enc      = (const float*)d_in[0];
  const float* x_mark_enc = (const float*)d_in[1];
  const float* x_dec      = (const float*)d_in[2];
  const float* x_mark_dec = (const float*)d_in[3];
  const float* conv_w     = (const float*)d_in[4];
  const float* mark_w     = (const float*)d_in[5];
  const float* qk_w       = (const float*)d_in[6];
  const float* v_w        = (const float*)d_in[7];
  const float* out_w      = (const float*)d_in[8];
  const float* out_b      = (const float*)d_in[9];
  const float* ln1_g      = (const float*)d_in[10];
  const float* ln1_b      = (const float*)d_in[11];
  const float* ln2_g      = (const float*)d_in[12];
  const float* ln2_b      = (const float*)d_in[13];
  const float* ffn_w1     = (const float*)d_in[14];
  const float* ffn_b1     = (const float*)d_in[15];
  const float* ffn_w2     = (const float*)d_in[16];
  const float* ffn_b2     = (const float*)d_in[17];
  const float* lnf_g      = (const float*)d_in[18];
  const float* lnf_b      = (const float*)d_in[19];
  const float* proj_w     = (const float*)d_in[20];
  const float* proj_b     = (const float*)d_in[21];
  const float* rotations  = (const float*)d_in[22];

  char* ws = (char*)d_ws;
  // R8-proven layout, all <= 241MB: A [0,64M) B [64,128M) C [128,192M) D [192,224M)
  double* h64   = (double*)(ws);               // A
  double* qk64  = (double*)(ws + 67108864);    // B
  double* v64   = (double*)(ws + 134217728);   // C (comb aliases)
  double* obuf  = (double*)(ws + 201326592);   // D 32MB: layer-1 o_rounds (16 bh)
  int*    stick = (int*)   (ws + 234881024);   // [224,226M)
  double* lse64 = (double*)(ws + 236978176);   // [226,230M) bh-global
  float*  lse32 = (float*) (ws + 236978176);
  double* comb  = v64;
  // layer-2 f32 aliases
  float* h32    = (float*)(ws + 201326592);    // D (obuf dead after layer-1 attn)
  float* qk32   = (float*)(ws + 134217728);    // C0 [128,160)
  float* v32    = (float*)(ws + 167772160);    // C1 [160,192)
  float* obuf32 = (float*)(ws + 67108864);     // B0 [64,96) (qk64 dead after bucket_sort)
  float* comb32 = (float*)(ws + 100663296);    // B1 [96,128)
  float* ao32   = (float*)(ws + 201326592);    // D (h32 dead after v-GEMM)
  float* hA32   = (float*)(ws + 134217728);    // C0 (qk32 dead after attn)
  float* hid32  = (float*)(ws);                // A+B [0,128M)
  float* y32    = (float*)(ws + 167772160);    // C1 (v32 dead)
  float* h2f    = (float*)(ws + 201326592);    // D (ao32 dead)
  float* hf32   = (float*)(ws);                // A0 (hid32 dead)

  embed_kernel<<<16384, 256, 0, stream>>>(x_enc, x_mark_enc, x_dec, x_mark_dec,
                                          conv_w, mark_w, h64);

  // ================= layer 0 : full fp64 =================
  dgemm_kernel<<<dim3(128,4), 256, 0, stream>>>(h64, qk_w, nullptr, qk64, nullptr,
                                                512, 512, 512, 4);
  dgemm_kernel<<<dim3(128,4), 256, 0, stream>>>(h64, v_w, nullptr, v64, nullptr,
                                                512, 512, 512, 4);
  bucket_sort_kernel<<<512, 256, 0, stream>>>(qk64, rotations, stick);
  for (int g = 0; g < 8; ++g) {
    lsh_attn_kernel<<<2048, 256, 0, stream>>>(qk64, v64, stick, obuf, lse64, g*16);
    combine_kernel<<<4096, 256, 0, stream>>>(obuf, lse64, comb, g*16);
  }
  dgemm_kernel<<<dim3(128,4), 256, 0, stream>>>(comb, out_w, out_b, qk64, nullptr,
                                                512, 512, 512, 1);
  ln_kernel<<<16384, 256, 0, stream>>>(h64, qk64, ln1_g, ln1_b, h64, nullptr);
  for (int c = 0; c < 4; ++c) {
    dgemm_kernel<<<dim3(128,4), 256, 0, stream>>>(h64, ffn_w1 + c*512,
                                                  ffn_b1 + c*512, qk64, nullptr,
                                                  512, 512, 2048, 3);
    dgemm_kernel<<<dim3(128,4), 256, 0, stream>>>(qk64, ffn_w2 + (size_t)c*512*512,
                                                  ffn_b2, comb, nullptr,
                                                  512, 512, 512, (c == 0) ? 1 : 16);
  }
  ln_kernel<<<16384, 256, 0, stream>>>(h64, comb, ln2_g, ln2_b, h64, h32);

  // ================= layer 1 : f64 decisions, f32 values =================
  sgemm_kernel<<<dim3(128,4), 256, 0, stream>>>(h32, v_w + 262144, nullptr, v32,
                                                512, 512, 4);
  dgemm_kernel<<<dim3(128,4), 256, 0, stream>>>(h64, qk_w + 262144, nullptr, qk64, qk32,
                                                512, 512, 512, 4 | 8);
  bucket_sort_kernel<<<512, 256, 0, stream>>>(qk64, rotations + 4096, stick);
  for (int g = 0; g < 4; ++g) {
    lsh_attn32_kernel<<<4096, 256, 0, stream>>>(qk32, v32, stick, obuf32, lse32, g*32);
    combine32_kernel<<<8192, 256, 0, stream>>>(obuf32, lse32, comb32, g*32);
  }
  sgemm_kernel<<<dim3(128,4), 256, 0, stream>>>(comb32, out_w + 262144, out_b + 512,
                                                ao32, 512, 512, 1);
  lnmx_kernel<<<16384, 256, 0, stream>>>(h64, ao32, ln1_g + 512, ln1_b + 512, hA32);
  sgemm_kernel<<<dim3(128,16), 256, 0, stream>>>(hA32, ffn_w1 + 1048576, ffn_b1 + 2048,
                                                 hid32, 2048, 512, 3);
  sgemm_kernel<<<dim3(128,4), 256, 0, stream>>>(hid32, ffn_w2 + 1048576, ffn_b2 + 512,
                                                y32, 512, 2048, 1);
  ln32_kernel<<<16384, 256, 0, stream>>>(hA32, y32, ln2_g + 512, ln2_b + 512, h2f);
  ln32_kernel<<<16384, 256, 0, stream>>>(h2f, nullptr, lnf_g, lnf_b, hf32);
  proj_kernel<<<4096, 64, 0, stream>>>(hf32, proj_w, proj_b, (float*)d_out);
}

// Round 11
// 4607.520 us; speedup vs baseline: 1.2330x; 1.2330x over previous
//
#include <hip/hip_runtime.h>
#include <math.h>

#define T_ 1024
#define NT_ 4096
#define MASKSELF64 -50000.0
#define MASKSELF32 -50000.0f
// WORKSPACE: ws_size ~= 256MB (R0/R9 wrote >=256MB -> OOB crash/garbage).
// This round uses up to 234MB.

typedef short bf16x8 __attribute__((ext_vector_type(8)));
typedef float f32x4 __attribute__((ext_vector_type(4)));

__device__ __forceinline__ unsigned short f2bf(float f) {
  unsigned int x = __float_as_uint(f);
  return (unsigned short)((x + 0x7FFFu + ((x >> 16) & 1u)) >> 16);
}

// ---------------- embedding (fp64) ----------------
__global__ __launch_bounds__(256)
void embed_kernel(const float* __restrict__ x_enc, const float* __restrict__ x_mark_enc,
                  const float* __restrict__ x_dec, const float* __restrict__ x_mark_dec,
                  const float* __restrict__ conv_w, const float* __restrict__ mark_w,
                  double* __restrict__ h) {
  int bt = blockIdx.x;
  int b = bt >> 10, t = bt & 1023;
  __shared__ double xs[3][7];
  __shared__ double xm[4];
  int tid = threadIdx.x;
  if (tid < 21) {
    int k = tid / 7, i = tid % 7;
    int tt = t + k - 1;
    if (tt < 0) tt += 1024;
    if (tt >= 1024) tt -= 1024;
    xs[k][i] = (double)((tt < 768) ? x_enc[((size_t)b*768 + tt)*7 + i]
                                   : x_dec[((size_t)b*512 + (tt - 512))*7 + i]);
  }
  if (tid >= 32 && tid < 36) {
    int m = tid - 32;
    xm[m] = (double)((t < 768) ? x_mark_enc[((size_t)b*768 + t)*4 + m]
                               : x_mark_dec[((size_t)b*512 + (t - 512))*4 + m]);
  }
  __syncthreads();
  for (int o = tid; o < 512; o += 256) {
    double acc = 0.0;
    #pragma unroll
    for (int k = 0; k < 3; ++k)
      #pragma unroll
      for (int i = 0; i < 7; ++i)
        acc += xs[k][i] * (double)conv_w[(o*7 + i)*3 + k];
    #pragma unroll
    for (int m = 0; m < 4; ++m) acc += xm[m] * (double)mark_w[m*512 + o];
    int j2 = o & ~1;
    double dv = exp((double)j2 * (-9.210340371976184 / 512.0));
    double arg = (double)t * dv;
    acc += (o & 1) ? cos(arg) : sin(arg);
    h[((size_t)b*1024 + t)*512 + o] = acc;
  }
}

// ---------------- fp64 scalar GEMM 128x128x16, 8x8 microtile, reg dbuf (R8-proven) ----------------
// flags: 1=+bias, 2=gelu(exact), 4=qkv layout, 8=dup f32 store (qkv only), 16=accumulate into C
__global__ __launch_bounds__(256)
void dgemm_kernel(const double* __restrict__ A, const float* __restrict__ Bm,
                  const float* __restrict__ bias, double* __restrict__ C,
                  float* __restrict__ C32, int N, int K, int ldb, int flags) {
  __shared__ double As[16][130];
  __shared__ float  Bs[16][132];
  int tid = threadIdx.x;
  int tx = tid & 15, ty = tid >> 4;
  int arow = blockIdx.x * 128;
  int bcol = blockIdx.y * 128;
  int am = tid >> 1, ak = (tid & 1) * 8;
  int bk = tid >> 4, bn = (tid & 15) * 8;
  const double* aptr = A + (size_t)(arow + am)*K + ak;
  const float*  bptr = Bm + (size_t)bk*ldb + bcol + bn;
  double acc[8][8];
  #pragma unroll
  for (int i=0;i<8;++i)
    #pragma unroll
    for (int j=0;j<8;++j) acc[i][j]=0.0;
  double2 av0 = *(const double2*)(aptr + 0);
  double2 av1 = *(const double2*)(aptr + 2);
  double2 av2 = *(const double2*)(aptr + 4);
  double2 av3 = *(const double2*)(aptr + 6);
  float4 bv0 = *(const float4*)(bptr);
  float4 bv1 = *(const float4*)(bptr + 4);
  for (int k0 = 0; k0 < K; k0 += 16) {
    As[ak+0][am] = av0.x; As[ak+1][am] = av0.y;
    As[ak+2][am] = av1.x; As[ak+3][am] = av1.y;
    As[ak+4][am] = av2.x; As[ak+5][am] = av2.y;
    As[ak+6][am] = av3.x; As[ak+7][am] = av3.y;
    *(float4*)&Bs[bk][bn]   = bv0;
    *(float4*)&Bs[bk][bn+4] = bv1;
    __syncthreads();
    if (k0 + 16 < K) {
      aptr += 16;
      bptr += (size_t)16*ldb;
      av0 = *(const double2*)(aptr + 0);
      av1 = *(const double2*)(aptr + 2);
      av2 = *(const double2*)(aptr + 4);
      av3 = *(const double2*)(aptr + 6);
      bv0 = *(const float4*)(bptr);
      bv1 = *(const float4*)(bptr + 4);
    }
    #pragma unroll
    for (int kk=0;kk<16;++kk) {
      double a[8];
      *(double2*)&a[0] = *(const double2*)&As[kk][2*ty];
      *(double2*)&a[2] = *(const double2*)&As[kk][2*ty+32];
      *(double2*)&a[4] = *(const double2*)&As[kk][2*ty+64];
      *(double2*)&a[6] = *(const double2*)&As[kk][2*ty+96];
      float2 f0 = *(const float2*)&Bs[kk][2*tx];
      float2 f1 = *(const float2*)&Bs[kk][2*tx+32];
      float2 f2 = *(const float2*)&Bs[kk][2*tx+64];
      float2 f3 = *(const float2*)&Bs[kk][2*tx+96];
      double b[8];
      b[0]=(double)f0.x; b[1]=(double)f0.y; b[2]=(double)f1.x; b[3]=(double)f1.y;
      b[4]=(double)f2.x; b[5]=(double)f2.y; b[6]=(double)f3.x; b[7]=(double)f3.y;
      #pragma unroll
      for (int i=0;i<8;++i)
        #pragma unroll
        for (int j=0;j<8;++j) acc[i][j] += a[i]*b[j];
    }
    __syncthreads();
  }
  #pragma unroll
  for (int i=0;i<8;++i) {
    int row = arow + 2*ty + (i&1) + 32*(i>>1);
    #pragma unroll
    for (int j=0;j<8;++j) {
      int col = bcol + 2*tx + (j&1) + 32*(j>>1);
      double cv = acc[i][j];
      if (flags & 1) cv += (double)bias[col];
      if (flags & 2) cv = 0.5*cv*(1.0 + erf(cv*0.70710678118654752440));
      if (flags & 4) {
        int b_ = row >> 10, t = row & 1023;
        int hd = col >> 6, dd = col & 63;
        size_t idx = (((size_t)b_*8 + hd)*1024 + t)*64 + dd;
        C[idx] = cv;
        if (flags & 8) C32[idx] = (float)cv;
      } else {
        size_t idx = (size_t)row*N + col;
        if (flags & 16) cv += C[idx];
        C[idx] = cv;
      }
    }
  }
}

// ---------------- fp32 GEMM 128x128x16, 8x8 microtile, reg dbuf (R8-proven) ----------------
// flags: 1=+bias, 2=gelu(exact), 4=qkv layout
__global__ __launch_bounds__(256)
void sgemm_kernel(const float* __restrict__ A, const float* __restrict__ Bm,
                  const float* __restrict__ bias, float* __restrict__ C,
                  int N, int K, int flags) {
  __shared__ float As[16][128];
  __shared__ float Bs[16][128];
  int tid = threadIdx.x;
  int tx = tid & 15, ty = tid >> 4;
  float acc[8][8];
  #pragma unroll
  for (int i=0;i<8;++i)
    #pragma unroll
    for (int j=0;j<8;++j) acc[i][j]=0.f;
  const int arow = blockIdx.x*128;
  const int bcol = blockIdx.y*128;
  int e0 = tid*2, e1 = tid*2 + 1;
  int ra0 = e0 >> 2, ca0 = (e0 & 3)*4;
  int ra1 = e1 >> 2, ca1 = (e1 & 3)*4;
  int kb0 = e0 >> 5, cb0 = (e0 & 31)*4;
  int kb1 = e1 >> 5, cb1 = (e1 & 31)*4;
  const float* pA0 = A + (size_t)(arow + ra0)*K + ca0;
  const float* pA1 = A + (size_t)(arow + ra1)*K + ca1;
  const float* pB0 = Bm + (size_t)kb0*N + bcol + cb0;
  const float* pB1 = Bm + (size_t)kb1*N + bcol + cb1;
  float4 va0 = *(const float4*)pA0;
  float4 va1 = *(const float4*)pA1;
  float4 vb0 = *(const float4*)pB0;
  float4 vb1 = *(const float4*)pB1;
  for (int k0 = 0; k0 < K; k0 += 16) {
    As[ca0+0][ra0]=va0.x; As[ca0+1][ra0]=va0.y; As[ca0+2][ra0]=va0.z; As[ca0+3][ra0]=va0.w;
    As[ca1+0][ra1]=va1.x; As[ca1+1][ra1]=va1.y; As[ca1+2][ra1]=va1.z; As[ca1+3][ra1]=va1.w;
    *(float4*)&Bs[kb0][cb0] = vb0;
    *(float4*)&Bs[kb1][cb1] = vb1;
    __syncthreads();
    if (k0 + 16 < K) {
      pA0 += 16; pA1 += 16;
      pB0 += (size_t)16*N; pB1 += (size_t)16*N;
      va0 = *(const float4*)pA0;
      va1 = *(const float4*)pA1;
      vb0 = *(const float4*)pB0;
      vb1 = *(const float4*)pB1;
    }
    #pragma unroll
    for (int kk=0;kk<16;++kk) {
      float a[8], bb[8];
      #pragma unroll
      for (int i=0;i<8;++i) a[i] = As[kk][ty + 16*i];
      #pragma unroll
      for (int j=0;j<8;++j) bb[j] = Bs[kk][tx + 16*j];
      #pragma unroll
      for (int i=0;i<8;++i)
        #pragma unroll
        for (int j=0;j<8;++j) acc[i][j] += a[i]*bb[j];
    }
    __syncthreads();
  }
  #pragma unroll
  for (int i=0;i<8;++i) {
    int row = arow + ty + 16*i;
    #pragma unroll
    for (int j=0;j<8;++j) {
      int col = bcol + tx + 16*j;
      float cv = acc[i][j];
      if (flags & 1) cv += bias[col];
      if (flags & 2) cv = 0.5f*cv*(1.0f + erff(cv*0.70710678118654752f));
      if (flags & 4) {
        int b = row >> 10, t = row & 1023;
        int hd = col >> 6, dd = col & 63;
        C[(((size_t)b*8 + hd)*1024 + t)*64 + dd] = cv;
      } else {
        C[(size_t)row*N + col] = cv;
      }
    }
  }
}

// ---------------- weight transpose + bf16 convert: w[K][N] -> wt[N][K] bf16 ----------------
__global__ __launch_bounds__(256)
void convert_wt_kernel(const float* __restrict__ w, unsigned short* __restrict__ wt,
                       int K, int N) {
  int total = K * N;
  for (int i = blockIdx.x*256 + threadIdx.x; i < total; i += gridDim.x*256) {
    int n = i / K, k = i - n*K;
    wt[i] = f2bf(w[(size_t)k*N + n]);
  }
}

// ---------------- bf16 MFMA GEMM 128x128x32: A[M][K]bf16 x Bt[N][K]bf16 -> C[M][N] ----------------
// Fragment layout per m89-verified spec: A m=lane&15,k=(lane>>4)*8+e; B n=lane&15,same k;
// D col=lane&15, row=(lane>>4)*4+reg.  flags: 1=+bias, 2=gelu, 8=bf16 output
__global__ __launch_bounds__(256)
void bgemm_kernel(const unsigned short* __restrict__ A, const unsigned short* __restrict__ Bt,
                  const float* __restrict__ bias, float* __restrict__ Cf,
                  unsigned short* __restrict__ C16, int N, int K, int flags) {
  __shared__ unsigned short As[128*32];
  __shared__ unsigned short Bs[128*32];
  int tid = threadIdx.x;
  int lane = tid & 63, wave = tid >> 6;
  int wr = wave >> 1, wc = wave & 1;
  int l15 = lane & 15, l4 = lane >> 4;
  int arow = blockIdx.x * 128, bcol = blockIdx.y * 128;
  int s0 = tid, s1 = tid + 256;                 // 512 16B slots per matrix
  int r0 = s0 >> 2, q0 = s0 & 3;
  int r1 = s1 >> 2, q1 = s1 & 3;
  const unsigned short* pA0 = A + (size_t)(arow + r0)*K + q0*8;
  const unsigned short* pA1 = A + (size_t)(arow + r1)*K + q1*8;
  const unsigned short* pB0 = Bt + (size_t)(bcol + r0)*K + q0*8;
  const unsigned short* pB1 = Bt + (size_t)(bcol + r1)*K + q1*8;
  f32x4 acc[4][4];
  #pragma unroll
  for (int i=0;i<4;++i)
    #pragma unroll
    for (int j=0;j<4;++j)
      #pragma unroll
      for (int r=0;r<4;++r) acc[i][j][r] = 0.f;
  uint4 a0 = *(const uint4*)pA0, a1 = *(const uint4*)pA1;
  uint4 b0 = *(const uint4*)pB0, b1 = *(const uint4*)pB1;
  for (int k0 = 0; k0 < K; k0 += 32) {
    *(uint4*)&As[r0*32 + q0*8] = a0;
    *(uint4*)&As[r1*32 + q1*8] = a1;
    *(uint4*)&Bs[r0*32 + q0*8] = b0;
    *(uint4*)&Bs[r1*32 + q1*8] = b1;
    __syncthreads();
    if (k0 + 32 < K) {
      pA0 += 32; pA1 += 32; pB0 += 32; pB1 += 32;
      a0 = *(const uint4*)pA0; a1 = *(const uint4*)pA1;
      b0 = *(const uint4*)pB0; b1 = *(const uint4*)pB1;
    }
    bf16x8 aF[4], bF[4];
    #pragma unroll
    for (int mt=0; mt<4; ++mt)
      aF[mt] = *(const bf16x8*)&As[(wr*64 + mt*16 + l15)*32 + l4*8];
    #pragma unroll
    for (int nt=0; nt<4; ++nt)
      bF[nt] = *(const bf16x8*)&Bs[(wc*64 + nt*16 + l15)*32 + l4*8];
    #pragma unroll
    for (int mt=0; mt<4; ++mt)
      #pragma unroll
      for (int nt=0; nt<4; ++nt)
        acc[mt][nt] = __builtin_amdgcn_mfma_f32_16x16x32_bf16(aF[mt], bF[nt], acc[mt][nt], 0, 0, 0);
    __syncthreads();
  }
  #pragma unroll
  for (int mt=0; mt<4; ++mt) {
    #pragma unroll
    for (int nt=0; nt<4; ++nt) {
      int col = bcol + wc*64 + nt*16 + l15;
      float bv = (flags & 1) ? bias[col] : 0.f;
      #pragma unroll
      for (int r=0; r<4; ++r) {
        int row = arow + wr*64 + mt*16 + l4*4 + r;
        float cv = acc[mt][nt][r] + bv;
        if (flags & 2) cv = 0.5f*cv*(1.0f + erff(cv*0.70710678118654752f));
        if (flags & 8) C16[(size_t)row*N + col] = f2bf(cv);
        else           Cf[(size_t)row*N + col] = cv;
      }
    }
  }
}

// ---------------- LSH bucket assignment + parallel two-level counting sort (fp64) ----------------
__global__ __launch_bounds__(256)
void bucket_sort_kernel(const double* __restrict__ qk, const float* __restrict__ rot,
                        int* __restrict__ sticker) {
  int bh = blockIdx.x >> 2, r = blockIdx.x & 3;
  __shared__ double rots[64][17];
  __shared__ unsigned char bucket[1024];
  __shared__ int cnt[32];
  __shared__ short H[16][32];
  __shared__ int off2[16][32];
  int tid = threadIdx.x;
  for (int idx = tid; idx < 1024; idx += 256) {
    int f = idx >> 4, i = idx & 15;
    rots[f][i] = (double)rot[(f*4 + r)*16 + i];
  }
  __syncthreads();
  for (int t = tid; t < 1024; t += 256) {
    const double* q = qk + ((size_t)bh*1024 + t)*64;
    double rv[16];
    #pragma unroll
    for (int i=0;i<16;++i) rv[i]=0.0;
    for (int f=0; f<64; ++f) {
      double qf = q[f];
      #pragma unroll
      for (int i=0;i<16;++i) rv[i] += qf * rots[f][i];
    }
    int best = 0; double bv = rv[0];
    #pragma unroll
    for (int i=1;i<16;++i) if (rv[i] > bv) { bv=rv[i]; best=i; }
    #pragma unroll
    for (int i=0;i<16;++i) { double nv = -rv[i]; if (nv > bv) { bv=nv; best=16+i; } }
    bucket[t] = (unsigned char)best;
  }
  __syncthreads();
  {
    int c = tid >> 4, s = tid & 15;
    int h0 = 0, h1 = 0;
    for (int t = c*64; t < c*64 + 64; ++t) {
      int b = bucket[t];
      h0 += (b == s);
      h1 += (b == s + 16);
    }
    H[c][s] = (short)h0;
    H[c][s+16] = (short)h1;
  }
  __syncthreads();
  if (tid < 32) {
    int s = 0;
    for (int c = 0; c < 16; ++c) s += H[c][tid];
    cnt[tid] = s;
  }
  __syncthreads();
  if (tid < 32) {
    int o = 0;
    for (int b = 0; b < tid; ++b) o += cnt[b];
    for (int c = 0; c < 16; ++c) { off2[c][tid] = o; o += H[c][tid]; }
  }
  __syncthreads();
  int* outp = sticker + (size_t)bh*NT_ + r*1024;
  #pragma unroll
  for (int q = 0; q < 2; ++q) {
    int p = tid + q*256;
    int c = p >> 5, b = p & 31;
    int pos = off2[c][b];
    for (int t = c*64; t < c*64 + 64; ++t)
      if (bucket[t] == (unsigned char)b) outp[pos++] = t;
  }
}

// ---------------- chunked LSH attention fp64 (16-bh groups, bh-global lse) ----------------
__global__ __launch_bounds__(256)
void lsh_attn_kernel(const double* __restrict__ qk, const double* __restrict__ v,
                     const int* __restrict__ sticker,
                     double* __restrict__ obuf, double* __restrict__ lse, int bh0) {
  int bh_l = blockIdx.x >> 7;
  int bh = bh0 + bh_l;
  int c  = blockIdx.x & 127;
  int cprev = (c + 127) & 127;
  __shared__ double kv[64][66];
  __shared__ double pp[32][66];
  __shared__ double rnorm[64];
  __shared__ int tk[64];
  int tid = threadIdx.x;
  if (tid < 64) {
    int chunk = (tid < 32) ? c : cprev;
    tk[tid] = sticker[(size_t)bh*NT_ + chunk*32 + (tid & 31)];
  }
  __syncthreads();
  for (int idx = tid; idx < 2048; idx += 256) {
    int j = idx >> 5, c2 = (idx & 31)*2;
    *(double2*)&kv[j][c2] = *(const double2*)(qk + ((size_t)bh*1024 + tk[j])*64 + c2);
  }
  __syncthreads();
  if (tid < 64) {
    double s = 0.0;
    #pragma unroll
    for (int f=0; f<64; ++f) { double x = kv[tid][f]; s += x*x; }
    rnorm[tid] = 1.0 / fmax(sqrt(s), 1e-12);
  }
  __syncthreads();
  int i = tid >> 3, sub = tid & 7;
  int ti = tk[i];
  double dots[8];
  double dmax = -1.0e300;
  #pragma unroll
  for (int jj=0; jj<8; ++jj) {
    int j = sub*8 + jj;
    double s = 0.0;
    #pragma unroll
    for (int f=0; f<64; ++f) s += kv[i][f] * kv[j][f];
    s *= rnorm[j] * 0.125;
    if (ti == tk[j]) s = MASKSELF64;
    dots[jj] = s;
    dmax = fmax(dmax, s);
  }
  #pragma unroll
  for (int w=1; w<8; w<<=1) dmax = fmax(dmax, __shfl_xor(dmax, w, 64));
  double esum = 0.0;
  #pragma unroll
  for (int jj=0; jj<8; ++jj) {
    double e = exp(dots[jj] - dmax);
    esum += e;
    pp[i][sub*8+jj] = e;
  }
  #pragma unroll
  for (int w=1; w<8; w<<=1) esum += __shfl_xor(esum, w, 64);
  __syncthreads();
  for (int idx = tid; idx < 2048; idx += 256) {
    int j = idx >> 5, c2 = (idx & 31)*2;
    *(double2*)&kv[j][c2] = *(const double2*)(v + ((size_t)bh*1024 + tk[j])*64 + c2);
  }
  __syncthreads();
  double ov[8];
  #pragma unroll
  for (int dd=0;dd<8;++dd) ov[dd]=0.0;
  for (int j=0;j<64;++j) {
    double p = pp[i][j];
    #pragma unroll
    for (int dd=0;dd<8;++dd) ov[dd] += p * kv[j][sub*8+dd];
  }
  double rinv = 1.0 / esum;
  int r = c >> 5;
  size_t ob = (((size_t)bh_l*4 + r)*1024 + ti)*64 + sub*8;
  #pragma unroll
  for (int dd=0;dd<8;++dd) obuf[ob + dd] = ov[dd]*rinv;
  if (sub == 0) lse[((size_t)bh*4 + r)*1024 + ti] = log(esum) + dmax;
}

// ---------------- combine rounds fp64 ----------------
__global__ __launch_bounds__(256)
void combine_kernel(const double* __restrict__ obuf, const double* __restrict__ lse,
                    double* __restrict__ comb, int bh0) {
  int g = blockIdx.x*4 + (threadIdx.x >> 6);
  int bh_l = g >> 10, t = g & 1023;
  int bh = bh0 + bh_l;
  int d = threadIdx.x & 63;
  double l[4];
  #pragma unroll
  for (int r=0;r<4;++r) l[r] = lse[((size_t)bh*4 + r)*1024 + t];
  double m = fmax(fmax(l[0],l[1]), fmax(l[2],l[3]));
  double e[4], s=0.0;
  #pragma unroll
  for (int r=0;r<4;++r){ e[r]=exp(l[r]-m); s+=e[r]; }
  double rs = 1.0/s;
  double o = 0.0;
  #pragma unroll
  for (int r=0;r<4;++r)
    o += e[r]*rs * obuf[(((size_t)bh_l*4 + r)*1024 + t)*64 + d];
  int b = bh >> 3, hd = bh & 7;
  comb[((size_t)b*1024 + t)*512 + hd*64 + d] = o;
}

// ---------------- chunked LSH attention fp32 (32-bh groups, bh-global lse) ----------------
__global__ __launch_bounds__(256)
void lsh_attn32_kernel(const float* __restrict__ qk, const float* __restrict__ v,
                       const int* __restrict__ sticker,
                       float* __restrict__ obuf, float* __restrict__ lse, int bh0) {
  int bh_l = blockIdx.x >> 7;
  int bh = bh0 + bh_l;
  int c  = blockIdx.x & 127;
  int cprev = (c + 127) & 127;
  __shared__ float kv[64][68];
  __shared__ float pp[32][68];
  __shared__ float rnorm[64];
  __shared__ int tk[64];
  int tid = threadIdx.x;
  if (tid < 64) {
    int chunk = (tid < 32) ? c : cprev;
    tk[tid] = sticker[(size_t)bh*NT_ + chunk*32 + (tid & 31)];
  }
  __syncthreads();
  for (int idx = tid; idx < 1024; idx += 256) {
    int j = idx >> 4, c4 = (idx & 15)*4;
    *(float4*)&kv[j][c4] = *(const float4*)(qk + ((size_t)bh*1024 + tk[j])*64 + c4);
  }
  __syncthreads();
  if (tid < 64) {
    float s = 0.f;
    #pragma unroll
    for (int f=0; f<64; ++f) { float x = kv[tid][f]; s += x*x; }
    rnorm[tid] = 1.0f / fmaxf(sqrtf(s), 1e-12f);
  }
  __syncthreads();
  int i = tid >> 3, sub = tid & 7;
  int ti = tk[i];
  float dots[8];
  float dmax = -1.0e30f;
  #pragma unroll
  for (int jj=0; jj<8; ++jj) {
    int j = sub*8 + jj;
    float s = 0.f;
    #pragma unroll
    for (int f=0; f<64; ++f) s += kv[i][f] * kv[j][f];
    s *= rnorm[j] * 0.125f;
    if (ti == tk[j]) s = MASKSELF32;
    dots[jj] = s;
    dmax = fmaxf(dmax, s);
  }
  #pragma unroll
  for (int w=1; w<8; w<<=1) dmax = fmaxf(dmax, __shfl_xor(dmax, w, 64));
  float esum = 0.f;
  #pragma unroll
  for (int jj=0; jj<8; ++jj) {
    float e = expf(dots[jj] - dmax);
    esum += e;
    pp[i][sub*8+jj] = e;
  }
  #pragma unroll
  for (int w=1; w<8; w<<=1) esum += __shfl_xor(esum, w, 64);
  __syncthreads();
  for (int idx = tid; idx < 1024; idx += 256) {
    int j = idx >> 4, c4 = (idx & 15)*4;
    *(float4*)&kv[j][c4] = *(const float4*)(v + ((size_t)bh*1024 + tk[j])*64 + c4);
  }
  __syncthreads();
  float ov[8];
  #pragma unroll
  for (int dd=0;dd<8;++dd) ov[dd]=0.f;
  for (int j=0;j<64;++j) {
    float p = pp[i][j];
    #pragma unroll
    for (int dd=0;dd<8;++dd) ov[dd] += p * kv[j][sub*8+dd];
  }
  float rinv = 1.0f / esum;
  int r = c >> 5;
  size_t ob = (((size_t)bh_l*4 + r)*1024 + ti)*64 + sub*8;
  #pragma unroll
  for (int dd=0;dd<8;++dd) obuf[ob + dd] = ov[dd]*rinv;
  if (sub == 0) lse[((size_t)bh*4 + r)*1024 + ti] = logf(esum) + dmax;
}

// ---------------- combine rounds fp32 ----------------
__global__ __launch_bounds__(256)
void combine32_kernel(const float* __restrict__ obuf, const float* __restrict__ lse,
                      float* __restrict__ comb, int bh0) {
  int g = blockIdx.x*4 + (threadIdx.x >> 6);
  int bh_l = g >> 10, t = g & 1023;
  int bh = bh0 + bh_l;
  int d = threadIdx.x & 63;
  float l[4];
  #pragma unroll
  for (int r=0;r<4;++r) l[r] = lse[((size_t)bh*4 + r)*1024 + t];
  float m = fmaxf(fmaxf(l[0],l[1]), fmaxf(l[2],l[3]));
  float e[4], s=0.f;
  #pragma unroll
  for (int r=0;r<4;++r){ e[r]=expf(l[r]-m); s+=e[r]; }
  float rs = 1.0f/s;
  float o = 0.f;
  #pragma unroll
  for (int r=0;r<4;++r)
    o += e[r]*rs * obuf[(((size_t)bh_l*4 + r)*1024 + t)*64 + d];
  int b = bh >> 3, hd = bh & 7;
  comb[((size_t)b*1024 + t)*512 + hd*64 + d] = o;
}

// ---------------- layernorm fp64 (optional residual, optional f32 dup) ----------------
__global__ __launch_bounds__(256)
void ln_kernel(const double* __restrict__ x, const double* __restrict__ res,
               const float* __restrict__ gw, const float* __restrict__ bw,
               double* __restrict__ outp, float* __restrict__ out32) {
  int row = blockIdx.x;
  int tid = threadIdx.x;
  const double* xr = x + (size_t)row*512;
  double v0 = xr[tid], v1 = xr[tid+256];
  if (res) { const double* rr = res + (size_t)row*512; v0 += rr[tid]; v1 += rr[tid+256]; }
  double s = v0 + v1;
  #pragma unroll
  for (int w=1; w<64; w<<=1) s += __shfl_xor(s, w, 64);
  __shared__ double red[4];
  int wid = tid >> 6, lane = tid & 63;
  if (lane == 0) red[wid] = s;
  __syncthreads();
  s = red[0]+red[1]+red[2]+red[3];
  double m = s * (1.0/512.0);
  double d0 = v0 - m, d1 = v1 - m;
  double q = d0*d0 + d1*d1;
  #pragma unroll
  for (int w=1; w<64; w<<=1) q += __shfl_xor(q, w, 64);
  __syncthreads();
  if (lane == 0) red[wid] = q;
  __syncthreads();
  q = red[0]+red[1]+red[2]+red[3];
  double var = q * (1.0/512.0);
  double rstd = 1.0 / sqrt(var + 1e-5);
  double o0 = d0*rstd*(double)gw[tid] + (double)bw[tid];
  double o1 = d1*rstd*(double)gw[tid+256] + (double)bw[tid+256];
  outp[(size_t)row*512 + tid]       = o0;
  outp[(size_t)row*512 + tid + 256] = o1;
  if (out32) {
    out32[(size_t)row*512 + tid]       = (float)o0;
    out32[(size_t)row*512 + tid + 256] = (float)o1;
  }
}

// ---------------- layernorm: x f64 + res f32 -> f32 (+ bf16 dup) ----------------
__global__ __launch_bounds__(256)
void lnmx_kernel(const double* __restrict__ x, const float* __restrict__ res,
                 const float* __restrict__ gw, const float* __restrict__ bw,
                 float* __restrict__ out32, unsigned short* __restrict__ out16) {
  int row = blockIdx.x;
  int tid = threadIdx.x;
  const double* xr = x + (size_t)row*512;
  const float*  rr = res + (size_t)row*512;
  double v0 = xr[tid] + (double)rr[tid];
  double v1 = xr[tid+256] + (double)rr[tid+256];
  double s = v0 + v1;
  #pragma unroll
  for (int w=1; w<64; w<<=1) s += __shfl_xor(s, w, 64);
  __shared__ double red[4];
  int wid = tid >> 6, lane = tid & 63;
  if (lane == 0) red[wid] = s;
  __syncthreads();
  s = red[0]+red[1]+red[2]+red[3];
  double m = s * (1.0/512.0);
  double d0 = v0 - m, d1 = v1 - m;
  double q = d0*d0 + d1*d1;
  #pragma unroll
  for (int w=1; w<64; w<<=1) q += __shfl_xor(q, w, 64);
  __syncthreads();
  if (lane == 0) red[wid] = q;
  __syncthreads();
  q = red[0]+red[1]+red[2]+red[3];
  double rstd = 1.0 / sqrt(q * (1.0/512.0) + 1e-5);
  float o0 = (float)(d0*rstd*(double)gw[tid] + (double)bw[tid]);
  float o1 = (float)(d1*rstd*(double)gw[tid+256] + (double)bw[tid+256]);
  out32[(size_t)row*512 + tid]       = o0;
  out32[(size_t)row*512 + tid + 256] = o1;
  out16[(size_t)row*512 + tid]       = f2bf(o0);
  out16[(size_t)row*512 + tid + 256] = f2bf(o1);
}

// ---------------- layernorm f32 in/out (double stats), optional residual ----------------
__global__ __launch_bounds__(256)
void ln32_kernel(const float* __restrict__ x, const float* __restrict__ res,
                 const float* __restrict__ gw, const float* __restrict__ bw,
                 float* __restrict__ out32) {
  int row = blockIdx.x;
  int tid = threadIdx.x;
  const float* xr = x + (size_t)row*512;
  double v0 = (double)xr[tid], v1 = (double)xr[tid+256];
  if (res) { const float* rr = res + (size_t)row*512; v0 += (double)rr[tid]; v1 += (double)rr[tid+256]; }
  double s = v0 + v1;
  #pragma unroll
  for (int w=1; w<64; w<<=1) s += __shfl_xor(s, w, 64);
  __shared__ double red[4];
  int wid = tid >> 6, lane = tid & 63;
  if (lane == 0) red[wid] = s;
  __syncthreads();
  s = red[0]+red[1]+red[2]+red[3];
  double m = s * (1.0/512.0);
  double d0 = v0 - m, d1 = v1 - m;
  double q = d0*d0 + d1*d1;
  #pragma unroll
  for (int w=1; w<64; w<<=1) q += __shfl_xor(q, w, 64);
  __syncthreads();
  if (lane == 0) red[wid] = q;
  __syncthreads();
  q = red[0]+red[1]+red[2]+red[3];
  double rstd = 1.0 / sqrt(q * (1.0/512.0) + 1e-5);
  out32[(size_t)row*512 + tid]       = (float)(d0*rstd*(double)gw[tid] + (double)bw[tid]);
  out32[(size_t)row*512 + tid + 256] = (float)(d1*rstd*(double)gw[tid+256] + (double)bw[tid+256]);
}

// ---------------- final projection (f32 input, f64 accum, f32 store) ----------------
__global__ __launch_bounds__(64)
void proj_kernel(const float* __restrict__ hf, const float* __restrict__ pw,
                 const float* __restrict__ pb, float* __restrict__ outp) {
  int row = blockIdx.x;
  int b = row >> 8, tp = row & 255;
  const float* hr = hf + ((size_t)b*1024 + 768 + tp)*512;
  int lane = threadIdx.x;
  double acc[7];
  #pragma unroll
  for (int cc=0;cc<7;++cc) acc[cc]=0.0;
  for (int d = lane; d < 512; d += 64) {
    double hv = (double)hr[d];
    #pragma unroll
    for (int cc=0;cc<7;++cc) acc[cc] += hv * (double)pw[d*7 + cc];
  }
  #pragma unroll
  for (int cc=0;cc<7;++cc) {
    double s = acc[cc];
    #pragma unroll
    for (int w=32;w>=1;w>>=1) s += __shfl_xor(s, w, 64);
    if (lane == 0) outp[(size_t)row*7 + cc] = (float)(s + (double)pb[cc]);
  }
}

extern "C" void kernel_launch(void* const* d_in, const int* in_sizes, int n_in,
                              void* d_out, int out_size, void* d_ws, size_t ws_size,
                              hipStream_t stream) {
  (void)in_sizes; (void)n_in; (void)out_size; (void)ws_size;
  const float* x_enc      = (const float*)d_in[0];
  const float* x_mark_enc = (const float*)d_in[1];
  const float* x_dec      = (const float*)d_in[2];
  const float* x_mark_dec = (const float*)d_in[3];
  const float* conv_w     = (const float*)d_in[4];
  const float* mark_w     = (const float*)d_in[5];
  const float* qk_w       = (const float*)d_in[6];
  const float* v_w        = (const float*)d_in[7];
  const float* out_w      = (const float*)d_in[8];
  const float* out_b      = (const float*)d_in[9];
  const float* ln1_g      = (const float*)d_in[10];
  const float* ln1_b      = (const float*)d_in[11];
  const float* ln2_g      = (const float*)d_in[12];
  const float* ln2_b      = (const float*)d_in[13];
  const float* ffn_w1     = (const float*)d_in[14];
  const float* ffn_b1     = (const float*)d_in[15];
  const float* ffn_w2     = (const float*)d_in[16];
  const float* ffn_b2     = (const float*)d_in[17];
  const float* lnf_g      = (const float*)d_in[18];
  const float* lnf_b      = (const float*)d_in[19];
  const float* proj_w     = (const float*)d_in[20];
  const float* proj_b     = (const float*)d_in[21];
  const float* rotations  = (const float*)d_in[22];

  char* ws = (char*)d_ws;
  // A [0,64M) B [64,128M) C [128,192M) D [192,224M); statics [224,234M)
  double* h64   = (double*)(ws);               // A
  double* qk64  = (double*)(ws + 67108864);    // B
  double* v64   = (double*)(ws + 134217728);   // C (comb aliases)
  double* obuf  = (double*)(ws + 201326592);   // D 32MB: layer-1 o_rounds (16 bh)
  int*    stick = (int*)   (ws + 234881024);   // [224,226M)
  double* lse64 = (double*)(ws + 236978176);   // [226,230M)
  float*  lse32 = (float*) (ws + 236978176);
  unsigned short* w1t = (unsigned short*)(ws + 241172480); // [230,232M) bf16 [2048][512]
  unsigned short* w2t = (unsigned short*)(ws + 243269632); // [232,234M) bf16 [512][2048]
  double* comb  = v64;
  // layer-2 aliases
  float* h32    = (float*)(ws + 201326592);    // D (obuf dead after layer-1 attn)
  float* qk32   = (float*)(ws + 134217728);    // C0 [128,160)
  float* v32    = (float*)(ws + 167772160);    // C1 [160,192)
  float* obuf32 = (float*)(ws + 67108864);     // B0 [64,96) (qk64 dead after bucket_sort)
  float* comb32 = (float*)(ws + 100663296);    // B1 [96,128)
  float* ao32   = (float*)(ws + 201326592);    // D (h32 dead after v-GEMM)
  float* hA32   = (float*)(ws + 134217728);    // C0 (qk32 dead after attn)
  unsigned short* hA16  = (unsigned short*)(ws + 67108864);  // B [64,80) 16MB (obuf32 dead)
  unsigned short* hid16 = (unsigned short*)(ws);             // A [0,64) 64MB (h64 dead after lnmx)
  float* y32    = (float*)(ws + 167772160);    // C1 (v32 dead)
  float* h2f    = (float*)(ws + 201326592);    // D (ao32 dead after lnmx)
  float* hf32   = (float*)(ws + 67108864);     // B [64,96) (hA16 dead after FFN1)

  embed_kernel<<<16384, 256, 0, stream>>>(x_enc, x_mark_enc, x_dec, x_mark_dec,
                                          conv_w, mark_w, h64);
  // one-time layer-2 FFN weight transpose+bf16 (constant inputs)
  convert_wt_kernel<<<2048, 256, 0, stream>>>(ffn_w1 + 1048576, w1t, 512, 2048);
  convert_wt_kernel<<<2048, 256, 0, stream>>>(ffn_w2 + 1048576, w2t, 2048, 512);

  // ================= layer 0 : full fp64 =================
  dgemm_kernel<<<dim3(128,4), 256, 0, stream>>>(h64, qk_w, nullptr, qk64, nullptr,
                                                512, 512, 512, 4);
  dgemm_kernel<<<dim3(128,4), 256, 0, stream>>>(h64, v_w, nullptr, v64, nullptr,
                                                512, 512, 512, 4);
  bucket_sort_kernel<<<512, 256, 0, stream>>>(qk64, rotations, stick);
  for (int g = 0; g < 8; ++g) {
    lsh_attn_kernel<<<2048, 256, 0, stream>>>(qk64, v64, stick, obuf, lse64, g*16);
    combine_kernel<<<4096, 256, 0, stream>>>(obuf, lse64, comb, g*16);
  }
  dgemm_kernel<<<dim3(128,4), 256, 0, stream>>>(comb, out_w, out_b, qk64, nullptr,
                                                512, 512, 512, 1);
  ln_kernel<<<16384, 256, 0, stream>>>(h64, qk64, ln1_g, ln1_b, h64, nullptr);
  for (int c = 0; c < 4; ++c) {
    dgemm_kernel<<<dim3(128,4), 256, 0, stream>>>(h64, ffn_w1 + c*512,
                                                  ffn_b1 + c*512, qk64, nullptr,
                                                  512, 512, 2048, 3);
    dgemm_kernel<<<dim3(128,4), 256, 0, stream>>>(qk64, ffn_w2 + (size_t)c*512*512,
                                                  ffn_b2, comb, nullptr,
                                                  512, 512, 512, (c == 0) ? 1 : 16);
  }
  ln_kernel<<<16384, 256, 0, stream>>>(h64, comb, ln2_g, ln2_b, h64, h32);

  // ================= layer 1 : f64 decisions, f32/bf16 values =================
  sgemm_kernel<<<dim3(128,4), 256, 0, stream>>>(h32, v_w + 262144, nullptr, v32,
                                                512, 512, 4);
  dgemm_kernel<<<dim3(128,4), 256, 0, stream>>>(h64, qk_w + 262144, nullptr, qk64, qk32,
                                                512, 512, 512, 4 | 8);
  bucket_sort_kernel<<<512, 256, 0, stream>>>(qk64, rotations + 4096, stick);
  for (int g = 0; g < 4; ++g) {
    lsh_attn32_kernel<<<4096, 256, 0, stream>>>(qk32, v32, stick, obuf32, lse32, g*32);
    combine32_kernel<<<8192, 256, 0, stream>>>(obuf32, lse32, comb32, g*32);
  }
  sgemm_kernel<<<dim3(128,4), 256, 0, stream>>>(comb32, out_w + 262144, out_b + 512,
                                                ao32, 512, 512, 1);
  lnmx_kernel<<<16384, 256, 0, stream>>>(h64, ao32, ln1_g + 512, ln1_b + 512, hA32, hA16);
  // FFN via bf16 MFMA: hid16 = bf16(gelu(hA16 @ w1 + b1)); y32 = hid16 @ w2 + b2
  bgemm_kernel<<<dim3(128,16), 256, 0, stream>>>(hA16, w1t, ffn_b1 + 2048,
                                                 nullptr, hid16, 2048, 512, 1|2|8);
  bgemm_kernel<<<dim3(128,4), 256, 0, stream>>>(hid16, w2t, ffn_b2 + 512,
                                                y32, nullptr, 512, 2048, 1);
  ln32_kernel<<<16384, 256, 0, stream>>>(hA32, y32, ln2_g + 512, ln2_b + 512, h2f);
  ln32_kernel<<<16384, 256, 0, stream>>>(h2f, nullptr, lnf_g, lnf_b, hf32);
  proj_kernel<<<4096, 64, 0, stream>>>(hf32, proj_w, proj_b, (float*)d_out);
}

// Round 12
// 4551.030 us; speedup vs baseline: 1.2483x; 1.0124x over previous
//
#include <hip/hip_runtime.h>
#include <math.h>

#define T_ 1024
#define NT_ 4096
#define MASKSELF64 -50000.0
#define MASKSELF32 -50000.0f
// WORKSPACE: ws_size ~= 256MB (R0/R9 wrote >=256MB -> OOB crash/garbage). Max used here: 235MB.

typedef short bf16x8 __attribute__((ext_vector_type(8)));
typedef float f32x4 __attribute__((ext_vector_type(4)));

__device__ __forceinline__ unsigned short f2bf(float f) {
  unsigned int x = __float_as_uint(f);
  return (unsigned short)((x + 0x7FFFu + ((x >> 16) & 1u)) >> 16);
}

// ---------------- embedding (fp64) ----------------
__global__ __launch_bounds__(256)
void embed_kernel(const float* __restrict__ x_enc, const float* __restrict__ x_mark_enc,
                  const float* __restrict__ x_dec, const float* __restrict__ x_mark_dec,
                  const float* __restrict__ conv_w, const float* __restrict__ mark_w,
                  double* __restrict__ h) {
  int bt = blockIdx.x;
  int b = bt >> 10, t = bt & 1023;
  __shared__ double xs[3][7];
  __shared__ double xm[4];
  int tid = threadIdx.x;
  if (tid < 21) {
    int k = tid / 7, i = tid % 7;
    int tt = t + k - 1;
    if (tt < 0) tt += 1024;
    if (tt >= 1024) tt -= 1024;
    xs[k][i] = (double)((tt < 768) ? x_enc[((size_t)b*768 + tt)*7 + i]
                                   : x_dec[((size_t)b*512 + (tt - 512))*7 + i]);
  }
  if (tid >= 32 && tid < 36) {
    int m = tid - 32;
    xm[m] = (double)((t < 768) ? x_mark_enc[((size_t)b*768 + t)*4 + m]
                               : x_mark_dec[((size_t)b*512 + (t - 512))*4 + m]);
  }
  __syncthreads();
  for (int o = tid; o < 512; o += 256) {
    double acc = 0.0;
    #pragma unroll
    for (int k = 0; k < 3; ++k)
      #pragma unroll
      for (int i = 0; i < 7; ++i)
        acc += xs[k][i] * (double)conv_w[(o*7 + i)*3 + k];
    #pragma unroll
    for (int m = 0; m < 4; ++m) acc += xm[m] * (double)mark_w[m*512 + o];
    int j2 = o & ~1;
    double dv = exp((double)j2 * (-9.210340371976184 / 512.0));
    double arg = (double)t * dv;
    acc += (o & 1) ? cos(arg) : sin(arg);
    h[((size_t)b*1024 + t)*512 + o] = acc;
  }
}

// ---------------- fp64 scalar GEMM 64x128 tile, K-step 16, 4x8 microtile, reg dbuf ----------------
// Per-output FMA chain identical to R6-R11 (ascending k). Grid dim3(M/64, N/128).
// flags: 1=+bias, 2=gelu(exact), 4=qkv layout, 8=dup f32 store (qkv only), 16=accumulate into C
__global__ __launch_bounds__(256)
void dgemm_kernel(const double* __restrict__ A, const float* __restrict__ Bm,
                  const float* __restrict__ bias, double* __restrict__ C,
                  float* __restrict__ C32, int N, int K, int ldb, int flags) {
  __shared__ double As[16][66];
  __shared__ float  Bs[16][132];
  int tid = threadIdx.x;
  int tx = tid & 15, ty = tid >> 4;
  int arow = blockIdx.x * 64;
  int bcol = blockIdx.y * 128;
  int am = tid >> 2, ak = (tid & 3) * 4;
  int bk = tid >> 4, bn = (tid & 15) * 8;
  const double* aptr = A + (size_t)(arow + am)*K + ak;
  const float*  bptr = Bm + (size_t)bk*ldb + bcol + bn;
  double acc[4][8];
  #pragma unroll
  for (int i=0;i<4;++i)
    #pragma unroll
    for (int j=0;j<8;++j) acc[i][j]=0.0;
  double2 av0 = *(const double2*)(aptr + 0);
  double2 av1 = *(const double2*)(aptr + 2);
  float4 bv0 = *(const float4*)(bptr);
  float4 bv1 = *(const float4*)(bptr + 4);
  for (int k0 = 0; k0 < K; k0 += 16) {
    As[ak+0][am] = av0.x; As[ak+1][am] = av0.y;
    As[ak+2][am] = av1.x; As[ak+3][am] = av1.y;
    *(float4*)&Bs[bk][bn]   = bv0;
    *(float4*)&Bs[bk][bn+4] = bv1;
    __syncthreads();
    if (k0 + 16 < K) {
      aptr += 16;
      bptr += (size_t)16*ldb;
      av0 = *(const double2*)(aptr + 0);
      av1 = *(const double2*)(aptr + 2);
      bv0 = *(const float4*)(bptr);
      bv1 = *(const float4*)(bptr + 4);
    }
    #pragma unroll
    for (int kk=0;kk<16;++kk) {
      double a[4], b[8];
      #pragma unroll
      for (int i=0;i<4;++i) a[i] = As[kk][ty + 16*i];
      #pragma unroll
      for (int j=0;j<8;++j) b[j] = (double)Bs[kk][tx + 16*j];
      #pragma unroll
      for (int i=0;i<4;++i)
        #pragma unroll
        for (int j=0;j<8;++j) acc[i][j] += a[i]*b[j];
    }
    __syncthreads();
  }
  #pragma unroll
  for (int i=0;i<4;++i) {
    int row = arow + ty + 16*i;
    #pragma unroll
    for (int j=0;j<8;++j) {
      int col = bcol + tx + 16*j;
      double cv = acc[i][j];
      if (flags & 1) cv += (double)bias[col];
      if (flags & 2) cv = 0.5*cv*(1.0 + erf(cv*0.70710678118654752440));
      if (flags & 4) {
        int b_ = row >> 10, t = row & 1023;
        int hd = col >> 6, dd = col & 63;
        size_t idx = (((size_t)b_*8 + hd)*1024 + t)*64 + dd;
        C[idx] = cv;
        if (flags & 8) C32[idx] = (float)cv;
      } else {
        size_t idx = (size_t)row*N + col;
        if (flags & 16) cv += C[idx];
        C[idx] = cv;
      }
    }
  }
}

// ---------------- weight transpose + bf16 convert: w[K][N] -> wt[N][K] bf16 ----------------
__global__ __launch_bounds__(256)
void convert_wt_kernel(const float* __restrict__ w, unsigned short* __restrict__ wt,
                       int K, int N) {
  int total = K * N;
  for (int i = blockIdx.x*256 + threadIdx.x; i < total; i += gridDim.x*256) {
    int n = i / K, k = i - n*K;
    wt[i] = f2bf(w[(size_t)k*N + n]);
  }
}

// ---------------- bf16 MFMA GEMM 128x128x32: A[M][K]bf16 x Bt[N][K]bf16 -> C[M][N] ----------------
// flags: 1=+bias, 2=gelu, 4=qkv layout, 8=bf16 output
__global__ __launch_bounds__(256)
void bgemm_kernel(const unsigned short* __restrict__ A, const unsigned short* __restrict__ Bt,
                  const float* __restrict__ bias, float* __restrict__ Cf,
                  unsigned short* __restrict__ C16, int N, int K, int flags) {
  __shared__ unsigned short As[128*40];   // row pad 32->40 shorts (80B): kills 8-way conflict
  __shared__ unsigned short Bs[128*40];
  int tid = threadIdx.x;
  int lane = tid & 63, wave = tid >> 6;
  int wr = wave >> 1, wc = wave & 1;
  int l15 = lane & 15, l4 = lane >> 4;
  int arow = blockIdx.x * 128, bcol = blockIdx.y * 128;
  int s0 = tid, s1 = tid + 256;
  int r0 = s0 >> 2, q0 = s0 & 3;
  int r1 = s1 >> 2, q1 = s1 & 3;
  const unsigned short* pA0 = A + (size_t)(arow + r0)*K + q0*8;
  const unsigned short* pA1 = A + (size_t)(arow + r1)*K + q1*8;
  const unsigned short* pB0 = Bt + (size_t)(bcol + r0)*K + q0*8;
  const unsigned short* pB1 = Bt + (size_t)(bcol + r1)*K + q1*8;
  f32x4 acc[4][4];
  #pragma unroll
  for (int i=0;i<4;++i)
    #pragma unroll
    for (int j=0;j<4;++j)
      #pragma unroll
      for (int r=0;r<4;++r) acc[i][j][r] = 0.f;
  uint4 a0 = *(const uint4*)pA0, a1 = *(const uint4*)pA1;
  uint4 b0 = *(const uint4*)pB0, b1 = *(const uint4*)pB1;
  for (int k0 = 0; k0 < K; k0 += 32) {
    *(uint4*)&As[r0*40 + q0*8] = a0;
    *(uint4*)&As[r1*40 + q1*8] = a1;
    *(uint4*)&Bs[r0*40 + q0*8] = b0;
    *(uint4*)&Bs[r1*40 + q1*8] = b1;
    __syncthreads();
    if (k0 + 32 < K) {
      pA0 += 32; pA1 += 32; pB0 += 32; pB1 += 32;
      a0 = *(const uint4*)pA0; a1 = *(const uint4*)pA1;
      b0 = *(const uint4*)pB0; b1 = *(const uint4*)pB1;
    }
    bf16x8 aF[4], bF[4];
    #pragma unroll
    for (int mt=0; mt<4; ++mt)
      aF[mt] = *(const bf16x8*)&As[(wr*64 + mt*16 + l15)*40 + l4*8];
    #pragma unroll
    for (int nt=0; nt<4; ++nt)
      bF[nt] = *(const bf16x8*)&Bs[(wc*64 + nt*16 + l15)*40 + l4*8];
    #pragma unroll
    for (int mt=0; mt<4; ++mt)
      #pragma unroll
      for (int nt=0; nt<4; ++nt)
        acc[mt][nt] = __builtin_amdgcn_mfma_f32_16x16x32_bf16(aF[mt], bF[nt], acc[mt][nt], 0, 0, 0);
    __syncthreads();
  }
  #pragma unroll
  for (int mt=0; mt<4; ++mt) {
    #pragma unroll
    for (int nt=0; nt<4; ++nt) {
      int col = bcol + wc*64 + nt*16 + l15;
      float bv = (flags & 1) ? bias[col] : 0.f;
      #pragma unroll
      for (int r=0; r<4; ++r) {
        int row = arow + wr*64 + mt*16 + l4*4 + r;
        float cv = acc[mt][nt][r] + bv;
        if (flags & 2) cv = 0.5f*cv*(1.0f + erff(cv*0.70710678118654752f));
        if (flags & 4) {
          int b_ = row >> 10, t = row & 1023;
          int hd = col >> 6, dd = col & 63;
          Cf[(((size_t)b_*8 + hd)*1024 + t)*64 + dd] = cv;
        } else if (flags & 8) {
          C16[(size_t)row*N + col] = f2bf(cv);
        } else {
          Cf[(size_t)row*N + col] = cv;
        }
      }
    }
  }
}

// ---------------- LSH bucket assignment + parallel two-level counting sort (fp64) ----------------
__global__ __launch_bounds__(256)
void bucket_sort_kernel(const double* __restrict__ qk, const float* __restrict__ rot,
                        int* __restrict__ sticker) {
  int bh = blockIdx.x >> 2, r = blockIdx.x & 3;
  __shared__ double rots[64][17];
  __shared__ unsigned char bucket[1024];
  __shared__ int cnt[32];
  __shared__ short H[16][32];
  __shared__ int off2[16][32];
  int tid = threadIdx.x;
  for (int idx = tid; idx < 1024; idx += 256) {
    int f = idx >> 4, i = idx & 15;
    rots[f][i] = (double)rot[(f*4 + r)*16 + i];
  }
  __syncthreads();
  for (int t = tid; t < 1024; t += 256) {
    const double* q = qk + ((size_t)bh*1024 + t)*64;
    double rv[16];
    #pragma unroll
    for (int i=0;i<16;++i) rv[i]=0.0;
    for (int f=0; f<64; ++f) {
      double qf = q[f];
      #pragma unroll
      for (int i=0;i<16;++i) rv[i] += qf * rots[f][i];
    }
    int best = 0; double bv = rv[0];
    #pragma unroll
    for (int i=1;i<16;++i) if (rv[i] > bv) { bv=rv[i]; best=i; }
    #pragma unroll
    for (int i=0;i<16;++i) { double nv = -rv[i]; if (nv > bv) { bv=nv; best=16+i; } }
    bucket[t] = (unsigned char)best;
  }
  __syncthreads();
  {
    int c = tid >> 4, s = tid & 15;
    int h0 = 0, h1 = 0;
    for (int t = c*64; t < c*64 + 64; ++t) {
      int b = bucket[t];
      h0 += (b == s);
      h1 += (b == s + 16);
    }
    H[c][s] = (short)h0;
    H[c][s+16] = (short)h1;
  }
  __syncthreads();
  if (tid < 32) {
    int s = 0;
    for (int c = 0; c < 16; ++c) s += H[c][tid];
    cnt[tid] = s;
  }
  __syncthreads();
  if (tid < 32) {
    int o = 0;
    for (int b = 0; b < tid; ++b) o += cnt[b];
    for (int c = 0; c < 16; ++c) { off2[c][tid] = o; o += H[c][tid]; }
  }
  __syncthreads();
  int* outp = sticker + (size_t)bh*NT_ + r*1024;
  #pragma unroll
  for (int q = 0; q < 2; ++q) {
    int p = tid + q*256;
    int c = p >> 5, b = p & 31;
    int pos = off2[c][b];
    for (int t = c*64; t < c*64 + 64; ++t)
      if (bucket[t] == (unsigned char)b) outp[pos++] = t;
  }
}

// ---------------- chunked LSH attention fp64 (16-bh groups, bh-global lse) ----------------
__global__ __launch_bounds__(256)
void lsh_attn_kernel(const double* __restrict__ qk, const double* __restrict__ v,
                     const int* __restrict__ sticker,
                     double* __restrict__ obuf, double* __restrict__ lse, int bh0) {
  int bh_l = blockIdx.x >> 7;
  int bh = bh0 + bh_l;
  int c  = blockIdx.x & 127;
  int cprev = (c + 127) & 127;
  __shared__ double kv[64][66];
  __shared__ double pp[32][66];
  __shared__ double rnorm[64];
  __shared__ int tk[64];
  int tid = threadIdx.x;
  if (tid < 64) {
    int chunk = (tid < 32) ? c : cprev;
    tk[tid] = sticker[(size_t)bh*NT_ + chunk*32 + (tid & 31)];
  }
  __syncthreads();
  for (int idx = tid; idx < 2048; idx += 256) {
    int j = idx >> 5, c2 = (idx & 31)*2;
    *(double2*)&kv[j][c2] = *(const double2*)(qk + ((size_t)bh*1024 + tk[j])*64 + c2);
  }
  __syncthreads();
  if (tid < 64) {
    double s = 0.0;
    #pragma unroll
    for (int f=0; f<64; ++f) { double x = kv[tid][f]; s += x*x; }
    rnorm[tid] = 1.0 / fmax(sqrt(s), 1e-12);
  }
  __syncthreads();
  int i = tid >> 3, sub = tid & 7;
  int ti = tk[i];
  double dots[8];
  double dmax = -1.0e300;
  #pragma unroll
  for (int jj=0; jj<8; ++jj) {
    int j = sub*8 + jj;
    double s = 0.0;
    #pragma unroll
    for (int f=0; f<64; ++f) s += kv[i][f] * kv[j][f];
    s *= rnorm[j] * 0.125;
    if (ti == tk[j]) s = MASKSELF64;
    dots[jj] = s;
    dmax = fmax(dmax, s);
  }
  #pragma unroll
  for (int w=1; w<8; w<<=1) dmax = fmax(dmax, __shfl_xor(dmax, w, 64));
  double esum = 0.0;
  #pragma unroll
  for (int jj=0; jj<8; ++jj) {
    double e = exp(dots[jj] - dmax);
    esum += e;
    pp[i][sub*8+jj] = e;
  }
  #pragma unroll
  for (int w=1; w<8; w<<=1) esum += __shfl_xor(esum, w, 64);
  __syncthreads();
  for (int idx = tid; idx < 2048; idx += 256) {
    int j = idx >> 5, c2 = (idx & 31)*2;
    *(double2*)&kv[j][c2] = *(const double2*)(v + ((size_t)bh*1024 + tk[j])*64 + c2);
  }
  __syncthreads();
  double ov[8];
  #pragma unroll
  for (int dd=0;dd<8;++dd) ov[dd]=0.0;
  for (int j=0;j<64;++j) {
    double p = pp[i][j];
    #pragma unroll
    for (int dd=0;dd<8;++dd) ov[dd] += p * kv[j][sub*8+dd];
  }
  double rinv = 1.0 / esum;
  int r = c >> 5;
  size_t ob = (((size_t)bh_l*4 + r)*1024 + ti)*64 + sub*8;
  #pragma unroll
  for (int dd=0;dd<8;++dd) obuf[ob + dd] = ov[dd]*rinv;
  if (sub == 0) lse[((size_t)bh*4 + r)*1024 + ti] = log(esum) + dmax;
}

// ---------------- combine rounds fp64 ----------------
__global__ __launch_bounds__(256)
void combine_kernel(const double* __restrict__ obuf, const double* __restrict__ lse,
                    double* __restrict__ comb, int bh0) {
  int g = blockIdx.x*4 + (threadIdx.x >> 6);
  int bh_l = g >> 10, t = g & 1023;
  int bh = bh0 + bh_l;
  int d = threadIdx.x & 63;
  double l[4];
  #pragma unroll
  for (int r=0;r<4;++r) l[r] = lse[((size_t)bh*4 + r)*1024 + t];
  double m = fmax(fmax(l[0],l[1]), fmax(l[2],l[3]));
  double e[4], s=0.0;
  #pragma unroll
  for (int r=0;r<4;++r){ e[r]=exp(l[r]-m); s+=e[r]; }
  double rs = 1.0/s;
  double o = 0.0;
  #pragma unroll
  for (int r=0;r<4;++r)
    o += e[r]*rs * obuf[(((size_t)bh_l*4 + r)*1024 + t)*64 + d];
  int b = bh >> 3, hd = bh & 7;
  comb[((size_t)b*1024 + t)*512 + hd*64 + d] = o;
}

// ---------------- chunked LSH attention fp32 (32-bh groups, bh-global lse) ----------------
__global__ __launch_bounds__(256)
void lsh_attn32_kernel(const float* __restrict__ qk, const float* __restrict__ v,
                       const int* __restrict__ sticker,
                       float* __restrict__ obuf, float* __restrict__ lse, int bh0) {
  int bh_l = blockIdx.x >> 7;
  int bh = bh0 + bh_l;
  int c  = blockIdx.x & 127;
  int cprev = (c + 127) & 127;
  __shared__ float kv[64][68];
  __shared__ float pp[32][68];
  __shared__ float rnorm[64];
  __shared__ int tk[64];
  int tid = threadIdx.x;
  if (tid < 64) {
    int chunk = (tid < 32) ? c : cprev;
    tk[tid] = sticker[(size_t)bh*NT_ + chunk*32 + (tid & 31)];
  }
  __syncthreads();
  for (int idx = tid; idx < 1024; idx += 256) {
    int j = idx >> 4, c4 = (idx & 15)*4;
    *(float4*)&kv[j][c4] = *(const float4*)(qk + ((size_t)bh*1024 + tk[j])*64 + c4);
  }
  __syncthreads();
  if (tid < 64) {
    float s = 0.f;
    #pragma unroll
    for (int f=0; f<64; ++f) { float x = kv[tid][f]; s += x*x; }
    rnorm[tid] = 1.0f / fmaxf(sqrtf(s), 1e-12f);
  }
  __syncthreads();
  int i = tid >> 3, sub = tid & 7;
  int ti = tk[i];
  float dots[8];
  float dmax = -1.0e30f;
  #pragma unroll
  for (int jj=0; jj<8; ++jj) {
    int j = sub*8 + jj;
    float s = 0.f;
    #pragma unroll
    for (int f=0; f<64; ++f) s += kv[i][f] * kv[j][f];
    s *= rnorm[j] * 0.125f;
    if (ti == tk[j]) s = MASKSELF32;
    dots[jj] = s;
    dmax = fmaxf(dmax, s);
  }
  #pragma unroll
  for (int w=1; w<8; w<<=1) dmax = fmaxf(dmax, __shfl_xor(dmax, w, 64));
  float esum = 0.f;
  #pragma unroll
  for (int jj=0; jj<8; ++jj) {
    float e = expf(dots[jj] - dmax);
    esum += e;
    pp[i][sub*8+jj] = e;
  }
  #pragma unroll
  for (int w=1; w<8; w<<=1) esum += __shfl_xor(esum, w, 64);
  __syncthreads();
  for (int idx = tid; idx < 1024; idx += 256) {
    int j = idx >> 4, c4 = (idx & 15)*4;
    *(float4*)&kv[j][c4] = *(const float4*)(v + ((size_t)bh*1024 + tk[j])*64 + c4);
  }
  __syncthreads();
  float ov[8];
  #pragma unroll
  for (int dd=0;dd<8;++dd) ov[dd]=0.f;
  for (int j=0;j<64;++j) {
    float p = pp[i][j];
    #pragma unroll
    for (int dd=0;dd<8;++dd) ov[dd] += p * kv[j][sub*8+dd];
  }
  float rinv = 1.0f / esum;
  int r = c >> 5;
  size_t ob = (((size_t)bh_l*4 + r)*1024 + ti)*64 + sub*8;
  #pragma unroll
  for (int dd=0;dd<8;++dd) obuf[ob + dd] = ov[dd]*rinv;
  if (sub == 0) lse[((size_t)bh*4 + r)*1024 + ti] = logf(esum) + dmax;
}

// ---------------- combine rounds fp32 -> bf16 output ----------------
__global__ __launch_bounds__(256)
void combine32_kernel(const float* __restrict__ obuf, const float* __restrict__ lse,
                      unsigned short* __restrict__ comb16, int bh0) {
  int g = blockIdx.x*4 + (threadIdx.x >> 6);
  int bh_l = g >> 10, t = g & 1023;
  int bh = bh0 + bh_l;
  int d = threadIdx.x & 63;
  float l[4];
  #pragma unroll
  for (int r=0;r<4;++r) l[r] = lse[((size_t)bh*4 + r)*1024 + t];
  float m = fmaxf(fmaxf(l[0],l[1]), fmaxf(l[2],l[3]));
  float e[4], s=0.f;
  #pragma unroll
  for (int r=0;r<4;++r){ e[r]=expf(l[r]-m); s+=e[r]; }
  float rs = 1.0f/s;
  float o = 0.f;
  #pragma unroll
  for (int r=0;r<4;++r)
    o += e[r]*rs * obuf[(((size_t)bh_l*4 + r)*1024 + t)*64 + d];
  int b = bh >> 3, hd = bh & 7;
  comb16[((size_t)b*1024 + t)*512 + hd*64 + d] = f2bf(o);
}

// ---------------- layernorm fp64 (optional residual, optional f32 dup, optional bf16 dup) ----------------
__global__ __launch_bounds__(256)
void ln_kernel(const double* __restrict__ x, const double* __restrict__ res,
               const float* __restrict__ gw, const float* __restrict__ bw,
               double* __restrict__ outp, float* __restrict__ out32,
               unsigned short* __restrict__ out16) {
  int row = blockIdx.x;
  int tid = threadIdx.x;
  const double* xr = x + (size_t)row*512;
  double v0 = xr[tid], v1 = xr[tid+256];
  if (res) { const double* rr = res + (size_t)row*512; v0 += rr[tid]; v1 += rr[tid+256]; }
  double s = v0 + v1;
  #pragma unroll
  for (int w=1; w<64; w<<=1) s += __shfl_xor(s, w, 64);
  __shared__ double red[4];
  int wid = tid >> 6, lane = tid & 63;
  if (lane == 0) red[wid] = s;
  __syncthreads();
  s = red[0]+red[1]+red[2]+red[3];
  double m = s * (1.0/512.0);
  double d0 = v0 - m, d1 = v1 - m;
  double q = d0*d0 + d1*d1;
  #pragma unroll
  for (int w=1; w<64; w<<=1) q += __shfl_xor(q, w, 64);
  __syncthreads();
  if (lane == 0) red[wid] = q;
  __syncthreads();
  q = red[0]+red[1]+red[2]+red[3];
  double var = q * (1.0/512.0);
  double rstd = 1.0 / sqrt(var + 1e-5);
  double o0 = d0*rstd*(double)gw[tid] + (double)bw[tid];
  double o1 = d1*rstd*(double)gw[tid+256] + (double)bw[tid+256];
  outp[(size_t)row*512 + tid]       = o0;
  outp[(size_t)row*512 + tid + 256] = o1;
  if (out32) {
    out32[(size_t)row*512 + tid]       = (float)o0;
    out32[(size_t)row*512 + tid + 256] = (float)o1;
  }
  if (out16) {
    out16[(size_t)row*512 + tid]       = f2bf((float)o0);
    out16[(size_t)row*512 + tid + 256] = f2bf((float)o1);
  }
}

// ---------------- layernorm: x f64 + res f32 -> f32 (+ bf16 dup) ----------------
__global__ __launch_bounds__(256)
void lnmx_kernel(const double* __restrict__ x, const float* __restrict__ res,
                 const float* __restrict__ gw, const float* __restrict__ bw,
                 float* __restrict__ out32, unsigned short* __restrict__ out16) {
  int row = blockIdx.x;
  int tid = threadIdx.x;
  const double* xr = x + (size_t)row*512;
  const float*  rr = res + (size_t)row*512;
  double v0 = xr[tid] + (double)rr[tid];
  double v1 = xr[tid+256] + (double)rr[tid+256];
  double s = v0 + v1;
  #pragma unroll
  for (int w=1; w<64; w<<=1) s += __shfl_xor(s, w, 64);
  __shared__ double red[4];
  int wid = tid >> 6, lane = tid & 63;
  if (lane == 0) red[wid] = s;
  __syncthreads();
  s = red[0]+red[1]+red[2]+red[3];
  double m = s * (1.0/512.0);
  double d0 = v0 - m, d1 = v1 - m;
  double q = d0*d0 + d1*d1;
  #pragma unroll
  for (int w=1; w<64; w<<=1) q += __shfl_xor(q, w, 64);
  __syncthreads();
  if (lane == 0) red[wid] = q;
  __syncthreads();
  q = red[0]+red[1]+red[2]+red[3];
  double rstd = 1.0 / sqrt(q * (1.0/512.0) + 1e-5);
  float o0 = (float)(d0*rstd*(double)gw[tid] + (double)bw[tid]);
  float o1 = (float)(d1*rstd*(double)gw[tid+256] + (double)bw[tid+256]);
  out32[(size_t)row*512 + tid]       = o0;
  out32[(size_t)row*512 + tid + 256] = o1;
  out16[(size_t)row*512 + tid]       = f2bf(o0);
  out16[(size_t)row*512 + tid + 256] = f2bf(o1);
}

// ---------------- layernorm f32 in/out (double stats), optional residual ----------------
__global__ __launch_bounds__(256)
void ln32_kernel(const float* __restrict__ x, const float* __restrict__ res,
                 const float* __restrict__ gw, const float* __restrict__ bw,
                 float* __restrict__ out32) {
  int row = blockIdx.x;
  int tid = threadIdx.x;
  const float* xr = x + (size_t)row*512;
  double v0 = (double)xr[tid], v1 = (double)xr[tid+256];
  if (res) { const float* rr = res + (size_t)row*512; v0 += (double)rr[tid]; v1 += (double)rr[tid+256]; }
  double s = v0 + v1;
  #pragma unroll
  for (int w=1; w<64; w<<=1) s += __shfl_xor(s, w, 64);
  __shared__ double red[4];
  int wid = tid >> 6, lane = tid & 63;
  if (lane == 0) red[wid] = s;
  __syncthreads();
  s = red[0]+red[1]+red[2]+red[3];
  double m = s * (1.0/512.0);
  double d0 = v0 - m, d1 = v1 - m;
  double q = d0*d0 + d1*d1;
  #pragma unroll
  for (int w=1; w<64; w<<=1) q += __shfl_xor(q, w, 64);
  __syncthreads();
  if (lane == 0) red[wid] = q;
  __syncthreads();
  q = red[0]+red[1]+red[2]+red[3];
  double rstd = 1.0 / sqrt(q * (1.0/512.0) + 1e-5);
  out32[(size_t)row*512 + tid]       = (float)(d0*rstd*(double)gw[tid] + (double)bw[tid]);
  out32[(size_t)row*512 + tid + 256] = (float)(d1*rstd*(double)gw[tid+256] + (double)bw[tid+256]);
}

// ---------------- final projection (f32 input, f64 accum, f32 store) ----------------
__global__ __launch_bounds__(64)
void proj_kernel(const float* __restrict__ hf, const float* __restrict__ pw,
                 const float* __restrict__ pb, float* __restrict__ outp) {
  int row = blockIdx.x;
  int b = row >> 8, tp = row & 255;
  const float* hr = hf + ((size_t)b*1024 + 768 + tp)*512;
  int lane = threadIdx.x;
  double acc[7];
  #pragma unroll
  for (int cc=0;cc<7;++cc) acc[cc]=0.0;
  for (int d = lane; d < 512; d += 64) {
    double hv = (double)hr[d];
    #pragma unroll
    for (int cc=0;cc<7;++cc) acc[cc] += hv * (double)pw[d*7 + cc];
  }
  #pragma unroll
  for (int cc=0;cc<7;++cc) {
    double s = acc[cc];
    #pragma unroll
    for (int w=32;w>=1;w>>=1) s += __shfl_xor(s, w, 64);
    if (lane == 0) outp[(size_t)row*7 + cc] = (float)(s + (double)pb[cc]);
  }
}

extern "C" void kernel_launch(void* const* d_in, const int* in_sizes, int n_in,
                              void* d_out, int out_size, void* d_ws, size_t ws_size,
                              hipStream_t stream) {
  (void)in_sizes; (void)n_in; (void)out_size; (void)ws_size;
  const float* x_enc      = (const float*)d_in[0];
  const float* x_mark_enc = (const float*)d_in[1];
  const float* x_dec      = (const float*)d_in[2];
  const float* x_mark_dec = (const float*)d_in[3];
  const float* conv_w     = (const float*)d_in[4];
  const float* mark_w     = (const float*)d_in[5];
  const float* qk_w       = (const float*)d_in[6];
  const float* v_w        = (const float*)d_in[7];
  const float* out_w      = (const float*)d_in[8];
  const float* out_b      = (const float*)d_in[9];
  const float* ln1_g      = (const float*)d_in[10];
  const float* ln1_b      = (const float*)d_in[11];
  const float* ln2_g      = (const float*)d_in[12];
  const float* ln2_b      = (const float*)d_in[13];
  const float* ffn_w1     = (const float*)d_in[14];
  const float* ffn_b1     = (const float*)d_in[15];
  const float* ffn_w2     = (const float*)d_in[16];
  const float* ffn_b2     = (const float*)d_in[17];
  const float* lnf_g      = (const float*)d_in[18];
  const float* lnf_b      = (const float*)d_in[19];
  const float* proj_w     = (const float*)d_in[20];
  const float* proj_b     = (const float*)d_in[21];
  const float* rotations  = (const float*)d_in[22];

  char* ws = (char*)d_ws;
  // A [0,64M) B [64,128M) C [128,192M) D [192,224M); statics [224,235M)
  double* h64   = (double*)(ws);               // A
  double* qk64  = (double*)(ws + 67108864);    // B
  double* v64   = (double*)(ws + 134217728);   // C (comb aliases)
  double* obuf  = (double*)(ws + 201326592);   // D 32MB: layer-0 o_rounds (16 bh)
  int*    stick = (int*)   (ws + 234881024);   // [224,226M)
  double* lse64 = (double*)(ws + 236978176);   // [226,230M)
  float*  lse32 = (float*) (ws + 236978176);
  unsigned short* w1t = (unsigned short*)(ws + 241172480); // [230,232M) bf16 [2048][512]
  unsigned short* w2t = (unsigned short*)(ws + 243269632); // [232,234M) bf16 [512][2048]
  unsigned short* vwt = (unsigned short*)(ws + 245366784); // [234,234.5M) bf16 [512][512]
  unsigned short* owt = (unsigned short*)(ws + 245891072); // [234.5,235M) bf16 [512][512]
  double* comb  = v64;
  // layer-1 aliases
  unsigned short* h16 = (unsigned short*)(ws + 67108864);  // B [64,80) bf16 dup of layer-0 out
  float* qk32   = (float*)(ws + 134217728);    // C0 [128,160)
  float* v32    = (float*)(ws + 167772160);    // C1 [160,192)
  float* obuf32 = (float*)(ws + 67108864);     // B0 [64,96) (h16/qk64 dead by attn time)
  unsigned short* comb16 = (unsigned short*)(ws + 100663296); // B1 [96,112)
  float* ao32   = (float*)(ws + 201326592);    // D (obuf dead)
  float* hA32   = (float*)(ws + 134217728);    // C0 (qk32 dead after attn)
  unsigned short* hA16  = (unsigned short*)(ws + 67108864);  // B [64,80) (obuf32 dead)
  unsigned short* hid16 = (unsigned short*)(ws);             // A [0,64) (h64 dead after lnmx)
  float* y32    = (float*)(ws + 167772160);    // C1 (v32 dead)
  float* h2f    = (float*)(ws + 201326592);    // D (ao32 dead after lnmx)
  float* hf32   = (float*)(ws + 67108864);     // B (hA16 dead after FFN1)

  embed_kernel<<<16384, 256, 0, stream>>>(x_enc, x_mark_enc, x_dec, x_mark_dec,
                                          conv_w, mark_w, h64);
  // one-time layer-1 weight transposes to bf16 (constant inputs)
  convert_wt_kernel<<<2048, 256, 0, stream>>>(ffn_w1 + 1048576, w1t, 512, 2048);
  convert_wt_kernel<<<2048, 256, 0, stream>>>(ffn_w2 + 1048576, w2t, 2048, 512);
  convert_wt_kernel<<<512, 256, 0, stream>>>(v_w + 262144, vwt, 512, 512);
  convert_wt_kernel<<<512, 256, 0, stream>>>(out_w + 262144, owt, 512, 512);

  // ================= layer 0 : full fp64 =================
  dgemm_kernel<<<dim3(256,4), 256, 0, stream>>>(h64, qk_w, nullptr, qk64, nullptr,
                                                512, 512, 512, 4);
  dgemm_kernel<<<dim3(256,4), 256, 0, stream>>>(h64, v_w, nullptr, v64, nullptr,
                                                512, 512, 512, 4);
  bucket_sort_kernel<<<512, 256, 0, stream>>>(qk64, rotations, stick);
  for (int g = 0; g < 8; ++g) {
    lsh_attn_kernel<<<2048, 256, 0, stream>>>(qk64, v64, stick, obuf, lse64, g*16);
    combine_kernel<<<4096, 256, 0, stream>>>(obuf, lse64, comb, g*16);
  }
  dgemm_kernel<<<dim3(256,4), 256, 0, stream>>>(comb, out_w, out_b, qk64, nullptr,
                                                512, 512, 512, 1);
  ln_kernel<<<16384, 256, 0, stream>>>(h64, qk64, ln1_g, ln1_b, h64, nullptr, nullptr);
  for (int c = 0; c < 4; ++c) {
    dgemm_kernel<<<dim3(256,4), 256, 0, stream>>>(h64, ffn_w1 + c*512,
                                                  ffn_b1 + c*512, qk64, nullptr,
                                                  512, 512, 2048, 3);
    dgemm_kernel<<<dim3(256,4), 256, 0, stream>>>(qk64, ffn_w2 + (size_t)c*512*512,
                                                  ffn_b2, comb, nullptr,
                                                  512, 512, 512, (c == 0) ? 1 : 16);
  }
  ln_kernel<<<16384, 256, 0, stream>>>(h64, comb, ln2_g, ln2_b, h64, nullptr, h16);

  // ================= layer 1 : f64 decisions, bf16/f32 values =================
  bgemm_kernel<<<dim3(128,4), 256, 0, stream>>>(h16, vwt, nullptr, v32, nullptr,
                                                512, 512, 4);
  dgemm_kernel<<<dim3(256,4), 256, 0, stream>>>(h64, qk_w + 262144, nullptr, qk64, qk32,
                                                512, 512, 512, 4 | 8);
  bucket_sort_kernel<<<512, 256, 0, stream>>>(qk64, rotations + 4096, stick);
  for (int g = 0; g < 4; ++g) {
    lsh_attn32_kernel<<<4096, 256, 0, stream>>>(qk32, v32, stick, obuf32, lse32, g*32);
    combine32_kernel<<<8192, 256, 0, stream>>>(obuf32, lse32, comb16, g*32);
  }
  bgemm_kernel<<<dim3(128,4), 256, 0, stream>>>(comb16, owt, out_b + 512, ao32, nullptr,
                                                512, 512, 1);
  lnmx_kernel<<<16384, 256, 0, stream>>>(h64, ao32, ln1_g + 512, ln1_b + 512, hA32, hA16);
  bgemm_kernel<<<dim3(128,16), 256, 0, stream>>>(hA16, w1t, ffn_b1 + 2048,
                                                 nullptr, hid16, 2048, 512, 1|2|8);
  bgemm_kernel<<<dim3(128,4), 256, 0, stream>>>(hid16, w2t, ffn_b2 + 512,
                                                y32, nullptr, 512, 2048, 1);
  ln32_kernel<<<16384, 256, 0, stream>>>(hA32, y32, ln2_g + 512, ln2_b + 512, h2f);
  ln32_kernel<<<16384, 256, 0, stream>>>(h2f, nullptr, lnf_g, lnf_b, hf32);
  proj_kernel<<<4096, 64, 0, stream>>>(hf32, proj_w, proj_b, (float*)d_out);
}